// Round 1
// baseline (1250.272 us; speedup 1.0000x reference)
//
#include <hip/hip_runtime.h>
#include <math.h>

// ===========================================================================
// NEW branch-1 pipeline (used when workspace is large enough):
//   A) k_sims1:  per (b,n): fp64 cosine sims + stable top-40 -> 41 pixel ids
//   B) k_mlp_pix: per image: dense MLP (64->256 relu ->256) + L2-norm for ALL
//      16384 pixels -> ybuf (pixel-major). Coalesced feat reads, each element
//      read exactly once. 32 pixels/block, 41.5 KB LDS -> 3 blocks/CU.
//   C) k_gather1: out1[bn, mi, :] = ybuf[pix, :]  (contiguous 1KB row copies)
// Rationale: out1 rows are a pure per-pixel function (MLP commutes with the
// gather), so compute 131072 dense rows instead of 180224 gathered ones.
// ===========================================================================

__global__ __launch_bounds__(128) void k_sims1(
    const float* __restrict__ feat1, const int* __restrict__ patch_id1,
    const int* __restrict__ local_id1, int* __restrict__ idx)
{
    __shared__ float cen[64];
    __shared__ double sims[80];
    __shared__ double cnorm;

    const int row = blockIdx.x;          // 0..4095
    const int b = row >> 9;              // /512
    const int n = row & 511;
    const int tid = threadIdx.x;
    const float* fb = feat1 + (size_t)b * 64 * 16384;   // (C=64, HW=16384)
    const int pid = patch_id1[n];
    const int* lids = local_id1 + n * 80;

    if (tid < 64) cen[tid] = fb[(size_t)tid * 16384 + pid];
    __syncthreads();

    if (tid < 64) {
        double v = (double)cen[tid];
        double s = v * v;
        for (int o = 32; o > 0; o >>= 1) s += __shfl_down(s, o);
        if (tid == 0) { s = sqrt(s); cnorm = (s < 1e-12) ? 1e-12 : s; }
    }
    __syncthreads();

    if (tid < 80) {
        const int lpix = lids[tid];
        double d = 0.0, q = 0.0;
        for (int c = 0; c < 64; ++c) {
            double v = (double)fb[(size_t)c * 16384 + lpix];
            d += v * (double)cen[c];
            q += v * v;
        }
        double nl = sqrt(q); if (nl < 1e-12) nl = 1e-12;
        sims[tid] = d / (nl * cnorm);
    }
    __syncthreads();

    // stable top-40 via rank (matches jax.lax.top_k tie-break: lower idx first)
    if (tid < 80) {
        const double s = sims[tid];
        int rank = 0;
        for (int j = 0; j < 80; ++j) {
            const double sj = sims[j];
            rank += (sj > s) || (sj == s && j < tid);
        }
        if (rank < 40) idx[row * 41 + 1 + rank] = lids[tid];
    }
    if (tid == 0) idx[row * 41] = pid;
}

// Dense per-pixel MLP for one image. 32 pixels per block, 256 threads.
// wave g handles rows mb..mb+7; lane jg owns cols j0..j0+3 (j0 = 4*jg).
__global__ __launch_bounds__(256) void k_mlp_pix(
    const float* __restrict__ fb,       // feat1 + b*64*16384  (C=64, HW=16384)
    const float* __restrict__ W3, const float* __restrict__ b3,
    const float* __restrict__ W4, const float* __restrict__ b4,
    float* __restrict__ ybuf)           // (16384, 256)
{
    __shared__ __align__(16) float xs[32 * 68];    // 32 pixels x 64 ch (pad 68)
    __shared__ __align__(16) float t1s[32 * 256];  // relu(x @ W3^T + b3)

    const int tid = threadIdx.x;
    const int p0 = blockIdx.x * 32;

    // fill xs: coalesced read (each feat element read exactly once),
    // 68-float row pad -> only 4-way write conflicts (negligible, one-time).
    {
        const int p = tid & 31;
        const int cg = tid >> 5;            // 0..7
        #pragma unroll
        for (int k = 0; k < 8; ++k) {
            const int c = cg * 8 + k;
            xs[p * 68 + c] = fb[(size_t)c * 16384 + p0 + p];
        }
    }
    __syncthreads();

    const int jg = tid & 63;
    const int g = tid >> 6;
    const int j0 = jg * 4;
    const int mb = g * 8;

    // ---- stage 1: t1 = relu(xs @ W3^T + b3) ----
    {
        float acc[8][4];
        #pragma unroll
        for (int r = 0; r < 8; ++r) {
            acc[r][0] = 0.f; acc[r][1] = 0.f; acc[r][2] = 0.f; acc[r][3] = 0.f;
        }
        const float4* W3f = (const float4*)W3;   // row j: W3f[j*16 + c4]
        const float4* xsf = (const float4*)xs;   // row p: xsf[p*17 + c4]
        #pragma unroll 4
        for (int c4 = 0; c4 < 16; ++c4) {
            const float4 w0 = W3f[(j0 + 0) * 16 + c4];
            const float4 w1 = W3f[(j0 + 1) * 16 + c4];
            const float4 w2 = W3f[(j0 + 2) * 16 + c4];
            const float4 w3 = W3f[(j0 + 3) * 16 + c4];
            #pragma unroll
            for (int r = 0; r < 8; ++r) {
                const float4 x4 = xsf[(mb + r) * 17 + c4];  // LDS broadcast
                acc[r][0] += x4.x*w0.x + x4.y*w0.y + x4.z*w0.z + x4.w*w0.w;
                acc[r][1] += x4.x*w1.x + x4.y*w1.y + x4.z*w1.z + x4.w*w1.w;
                acc[r][2] += x4.x*w2.x + x4.y*w2.y + x4.z*w2.z + x4.w*w2.w;
                acc[r][3] += x4.x*w3.x + x4.y*w3.y + x4.z*w3.z + x4.w*w3.w;
            }
        }
        const float bb0 = b3[j0], bb1 = b3[j0+1], bb2 = b3[j0+2], bb3 = b3[j0+3];
        #pragma unroll
        for (int r = 0; r < 8; ++r) {
            float4 o4;
            o4.x = fmaxf(acc[r][0] + bb0, 0.f);
            o4.y = fmaxf(acc[r][1] + bb1, 0.f);
            o4.z = fmaxf(acc[r][2] + bb2, 0.f);
            o4.w = fmaxf(acc[r][3] + bb3, 0.f);
            *(float4*)&t1s[(mb + r) * 256 + j0] = o4;
        }
    }
    __syncthreads();

    // ---- stage 2: y = t1 @ W4^T + b4, L2-normalize, store ----
    {
        float acc[8][4];
        #pragma unroll
        for (int r = 0; r < 8; ++r) {
            acc[r][0] = 0.f; acc[r][1] = 0.f; acc[r][2] = 0.f; acc[r][3] = 0.f;
        }
        const float4* W4f = (const float4*)W4;   // row j: W4f[j*64 + j4]
        const float4* t1f = (const float4*)t1s;  // row p: t1f[p*64 + j4]
        #pragma unroll 2
        for (int j4 = 0; j4 < 64; ++j4) {
            const float4 w0 = W4f[(j0 + 0) * 64 + j4];
            const float4 w1 = W4f[(j0 + 1) * 64 + j4];
            const float4 w2 = W4f[(j0 + 2) * 64 + j4];
            const float4 w3 = W4f[(j0 + 3) * 64 + j4];
            #pragma unroll
            for (int r = 0; r < 8; ++r) {
                const float4 t4 = t1f[(mb + r) * 64 + j4];  // LDS broadcast
                acc[r][0] += t4.x*w0.x + t4.y*w0.y + t4.z*w0.z + t4.w*w0.w;
                acc[r][1] += t4.x*w1.x + t4.y*w1.y + t4.z*w1.z + t4.w*w1.w;
                acc[r][2] += t4.x*w2.x + t4.y*w2.y + t4.z*w2.z + t4.w*w2.w;
                acc[r][3] += t4.x*w3.x + t4.y*w3.y + t4.z*w3.z + t4.w*w3.w;
            }
        }
        const float bb0 = b4[j0], bb1 = b4[j0+1], bb2 = b4[j0+2], bb3 = b4[j0+3];
        #pragma unroll
        for (int r = 0; r < 8; ++r) {
            const float y0 = acc[r][0] + bb0;
            const float y1 = acc[r][1] + bb1;
            const float y2 = acc[r][2] + bb2;
            const float y3 = acc[r][3] + bb3;
            float p = y0*y0 + y1*y1 + y2*y2 + y3*y3;
            for (int o = 1; o < 64; o <<= 1) p += __shfl_xor(p, o);
            const float inv = 1.f / (sqrtf(p) + 1e-7f);
            float4 o4 = make_float4(y0*inv, y1*inv, y2*inv, y3*inv);
            *(float4*)&ybuf[(size_t)(p0 + mb + r) * 256 + j0] = o4;
        }
    }
}

// Gather normalized rows into out1 for one image (512 (b,n) rows).
__global__ __launch_bounds__(256) void k_gather1(
    const float* __restrict__ ybuf, const int* __restrict__ idxb,
    float* __restrict__ out1b)
{
    __shared__ int pix[41];
    const int n = blockIdx.x;            // 0..511
    const int tid = threadIdx.x;
    if (tid < 41) pix[tid] = idxb[n * 41 + tid];
    __syncthreads();
    const float4* yb4 = (const float4*)ybuf;
    float4* o4 = (float4*)(out1b + (size_t)n * 41 * 256);
    for (int e = tid; e < 41 * 64; e += 256) {
        const int mi = e >> 6, j4 = e & 63;
        o4[mi * 64 + j4] = yb4[pix[mi] * 64 + j4];
    }
}

// ===========================================================================
// FALLBACK: original fused branch-1 kernel (verified at 1323.6 us) — used
// when the workspace is too small for ybuf.
// ===========================================================================
__global__ __launch_bounds__(256) void k_branch1(
    const float* __restrict__ feat1, const int* __restrict__ patch_id1,
    const int* __restrict__ local_id1, const float* __restrict__ W3,
    const float* __restrict__ b3, const float* __restrict__ W4,
    const float* __restrict__ b4, float* __restrict__ out1)
{
    __shared__ __align__(16) float xs[44 * 64];
    __shared__ __align__(16) float t1s[44 * 256];
    __shared__ double sims[80];
    __shared__ int winners[40];
    __shared__ float cen[64];
    __shared__ double cnorm;

    const int row = blockIdx.x;
    const int b = row >> 9;
    const int n = row & 511;
    const int tid = threadIdx.x;
    const float* fb = feat1 + (size_t)b * 64 * 16384;
    const int pid = patch_id1[n];
    const int* lids = local_id1 + n * 80;

    if (tid < 64) cen[tid] = fb[(size_t)tid * 16384 + pid];
    __syncthreads();

    if (tid < 64) {
        double v = (double)cen[tid];
        double s = v * v;
        for (int o = 32; o > 0; o >>= 1) s += __shfl_down(s, o);
        if (tid == 0) { s = sqrt(s); cnorm = (s < 1e-12) ? 1e-12 : s; }
    }
    __syncthreads();

    if (tid < 80) {
        const int lpix = lids[tid];
        double d = 0.0, q = 0.0;
        for (int c = 0; c < 64; ++c) {
            double v = (double)fb[(size_t)c * 16384 + lpix];
            d += v * (double)cen[c];
            q += v * v;
        }
        double nl = sqrt(q); if (nl < 1e-12) nl = 1e-12;
        sims[tid] = d / (nl * cnorm);
    }
    __syncthreads();

    if (tid < 80) {
        const double s = sims[tid];
        int rank = 0;
        for (int j = 0; j < 80; ++j) {
            const double sj = sims[j];
            rank += (sj > s) || (sj == s && j < tid);
        }
        if (rank < 40) winners[rank] = tid;
    }
    __syncthreads();

    for (int m = tid; m < 44 * 64; m += 256) {
        const int mi = m >> 6, c = m & 63;
        float v;
        if (mi >= 1 && mi <= 40) v = fb[(size_t)c * 16384 + lids[winners[mi - 1]]];
        else v = cen[c];
        xs[m] = v;
    }
    __syncthreads();

    const int jg = tid & 63;
    const int g = tid >> 6;
    const int j0 = jg * 4;
    const int mb = g * 11;

    {
        float acc[11][4];
        #pragma unroll
        for (int r = 0; r < 11; ++r) {
            acc[r][0] = 0.f; acc[r][1] = 0.f; acc[r][2] = 0.f; acc[r][3] = 0.f;
        }
        const float4* W3f = (const float4*)W3;
        const float4* xsf = (const float4*)xs;
        #pragma unroll 4
        for (int c4 = 0; c4 < 16; ++c4) {
            const float4 w0 = W3f[(j0 + 0) * 16 + c4];
            const float4 w1 = W3f[(j0 + 1) * 16 + c4];
            const float4 w2 = W3f[(j0 + 2) * 16 + c4];
            const float4 w3 = W3f[(j0 + 3) * 16 + c4];
            #pragma unroll
            for (int r = 0; r < 11; ++r) {
                const float4 x4 = xsf[(mb + r) * 16 + c4];
                acc[r][0] += x4.x*w0.x + x4.y*w0.y + x4.z*w0.z + x4.w*w0.w;
                acc[r][1] += x4.x*w1.x + x4.y*w1.y + x4.z*w1.z + x4.w*w1.w;
                acc[r][2] += x4.x*w2.x + x4.y*w2.y + x4.z*w2.z + x4.w*w2.w;
                acc[r][3] += x4.x*w3.x + x4.y*w3.y + x4.z*w3.z + x4.w*w3.w;
            }
        }
        const float bb0 = b3[j0], bb1 = b3[j0+1], bb2 = b3[j0+2], bb3 = b3[j0+3];
        #pragma unroll
        for (int r = 0; r < 11; ++r) {
            float4 o4;
            o4.x = fmaxf(acc[r][0] + bb0, 0.f);
            o4.y = fmaxf(acc[r][1] + bb1, 0.f);
            o4.z = fmaxf(acc[r][2] + bb2, 0.f);
            o4.w = fmaxf(acc[r][3] + bb3, 0.f);
            *(float4*)&t1s[(mb + r) * 256 + j0] = o4;
        }
    }
    __syncthreads();

    {
        float acc[11][4];
        #pragma unroll
        for (int r = 0; r < 11; ++r) {
            acc[r][0] = 0.f; acc[r][1] = 0.f; acc[r][2] = 0.f; acc[r][3] = 0.f;
        }
        const float4* W4f = (const float4*)W4;
        const float4* t1f = (const float4*)t1s;
        #pragma unroll 2
        for (int j4 = 0; j4 < 64; ++j4) {
            const float4 w0 = W4f[(j0 + 0) * 64 + j4];
            const float4 w1 = W4f[(j0 + 1) * 64 + j4];
            const float4 w2 = W4f[(j0 + 2) * 64 + j4];
            const float4 w3 = W4f[(j0 + 3) * 64 + j4];
            #pragma unroll
            for (int r = 0; r < 11; ++r) {
                const float4 t4 = t1f[(mb + r) * 64 + j4];
                acc[r][0] += t4.x*w0.x + t4.y*w0.y + t4.z*w0.z + t4.w*w0.w;
                acc[r][1] += t4.x*w1.x + t4.y*w1.y + t4.z*w1.z + t4.w*w1.w;
                acc[r][2] += t4.x*w2.x + t4.y*w2.y + t4.z*w2.z + t4.w*w2.w;
                acc[r][3] += t4.x*w3.x + t4.y*w3.y + t4.z*w3.z + t4.w*w3.w;
            }
        }
        const float bb0 = b4[j0], bb1 = b4[j0+1], bb2 = b4[j0+2], bb3 = b4[j0+3];
        #pragma unroll
        for (int r = 0; r < 11; ++r) {
            const float y0 = acc[r][0] + bb0;
            const float y1 = acc[r][1] + bb1;
            const float y2 = acc[r][2] + bb2;
            const float y3 = acc[r][3] + bb3;
            float p = y0*y0 + y1*y1 + y2*y2 + y3*y3;
            for (int o = 1; o < 64; o <<= 1) p += __shfl_xor(p, o);
            const float inv = 1.f / (sqrtf(p) + 1e-7f);
            const int mi = mb + r;
            if (mi < 41) {
                float4 o4 = make_float4(y0*inv, y1*inv, y2*inv, y3*inv);
                *(float4*)&out1[((size_t)row * 41 + mi) * 256 + j0] = o4;
            }
        }
    }
}

// ---------------------------------------------------------------------------
// Branch 0 kernels (unchanged, verified)
// ---------------------------------------------------------------------------
__global__ __launch_bounds__(64) void k_sample0(
    const float* __restrict__ feat0, const int* __restrict__ patch_id0,
    const int* __restrict__ local_id0, float* __restrict__ x0m)
{
    __shared__ float cen[512];
    __shared__ float loc[8][512];
    __shared__ double sims[8];
    __shared__ int winners[4];
    __shared__ double cnorm;

    const int row = blockIdx.x;
    const int b = row >> 6;
    const int n = row & 63;
    const int t = threadIdx.x;
    const float* fb = feat0 + (size_t)b * 512 * 64;
    const int pid = patch_id0[n];

    for (int c = t; c < 512; c += 64) cen[c] = fb[(size_t)c * 64 + pid];
    for (int l = 0; l < 8; ++l) {
        const int lp = local_id0[n * 8 + l];
        for (int c = t; c < 512; c += 64) loc[l][c] = fb[(size_t)c * 64 + lp];
    }
    __syncthreads();

    double cs = 0.0;
    for (int c = t; c < 512; c += 64) { double v = (double)cen[c]; cs += v * v; }
    for (int o = 32; o > 0; o >>= 1) cs += __shfl_down(cs, o);
    if (t == 0) { cs = sqrt(cs); cnorm = (cs < 1e-12) ? 1e-12 : cs; }
    __syncthreads();

    for (int l = 0; l < 8; ++l) {
        double d = 0.0, q = 0.0;
        for (int c = t; c < 512; c += 64) {
            double v = (double)loc[l][c];
            d += v * (double)cen[c];
            q += v * v;
        }
        for (int o = 32; o > 0; o >>= 1) { d += __shfl_down(d, o); q += __shfl_down(q, o); }
        if (t == 0) {
            double nl = sqrt(q); if (nl < 1e-12) nl = 1e-12;
            sims[l] = d / (nl * cnorm);
        }
    }
    __syncthreads();

    if (t < 8) {
        const double s = sims[t];
        int rank = 0;
        for (int j = 0; j < 8; ++j) {
            const double sj = sims[j];
            rank += (sj > s) || (sj == s && j < t);
        }
        if (rank < 4) winners[rank] = t;
    }
    __syncthreads();

    for (int c = t; c < 512; c += 64) {
        float a = cen[c];
        for (int r = 0; r < 4; ++r) a += loc[winners[r]][c];
        x0m[(size_t)row * 512 + c] = a * 0.2f;
    }
}

__global__ __launch_bounds__(256) void k_gemm1(
    const float* __restrict__ x, const float* __restrict__ W1,
    const float* __restrict__ b1, float* __restrict__ h)
{
    __shared__ __align__(16) float xsr[512];
    const int i = blockIdx.y;
    const int j = blockIdx.x * 256 + threadIdx.x;
    for (int c = threadIdx.x; c < 512; c += 256) xsr[c] = x[(size_t)i * 512 + c];
    __syncthreads();
    const float4* wr = (const float4*)(W1 + (size_t)j * 512);
    const float4* xr = (const float4*)xsr;
    float acc = 0.f;
    #pragma unroll 4
    for (int k = 0; k < 128; ++k) {
        const float4 w = wr[k]; const float4 a = xr[k];
        acc += a.x*w.x + a.y*w.y + a.z*w.z + a.w*w.w;
    }
    h[(size_t)i * 1024 + j] = acc + b1[j];
}

__global__ __launch_bounds__(64) void k_bnstats(
    const float* __restrict__ h, float* __restrict__ mu, float* __restrict__ rstd)
{
    const int j = blockIdx.x;
    const int t = threadIdx.x;
    float s = 0.f, ss = 0.f;
    for (int i = t; i < 512; i += 64) {
        const float v = h[(size_t)i * 1024 + j];
        s += v; ss += v * v;
    }
    for (int o = 32; o > 0; o >>= 1) { s += __shfl_down(s, o); ss += __shfl_down(ss, o); }
    if (t == 0) {
        const float m = s * (1.f / 512.f);
        const float var = ss * (1.f / 512.f) - m * m;
        mu[j] = m;
        rstd[j] = rsqrtf(var + 1e-5f);
    }
}

__global__ __launch_bounds__(256) void k_bnapply(
    float* __restrict__ h, const float* __restrict__ mu, const float* __restrict__ rstd,
    const float* __restrict__ gamma, const float* __restrict__ beta)
{
    const int e = blockIdx.x * 256 + threadIdx.x;
    const int jb = (e & 255) * 4;
    float4 v = ((float4*)h)[e];
    v.x = fmaxf((v.x - mu[jb+0]) * rstd[jb+0] * gamma[jb+0] + beta[jb+0], 0.f);
    v.y = fmaxf((v.y - mu[jb+1]) * rstd[jb+1] * gamma[jb+1] + beta[jb+1], 0.f);
    v.z = fmaxf((v.z - mu[jb+2]) * rstd[jb+2] * gamma[jb+2] + beta[jb+2], 0.f);
    v.w = fmaxf((v.w - mu[jb+3]) * rstd[jb+3] * gamma[jb+3] + beta[jb+3], 0.f);
    ((float4*)h)[e] = v;
}

__global__ __launch_bounds__(256) void k_gemm2(
    const float* __restrict__ h, const float* __restrict__ W2,
    const float* __restrict__ b2, float* __restrict__ out0)
{
    __shared__ __align__(16) float hs[1024];
    const int i = blockIdx.x;
    const int j = threadIdx.x;
    for (int c = threadIdx.x; c < 1024; c += 256) hs[c] = h[(size_t)i * 1024 + c];
    __syncthreads();
    const float4* wr = (const float4*)(W2 + (size_t)j * 1024);
    const float4* hr = (const float4*)hs;
    float acc = 0.f;
    #pragma unroll 4
    for (int k = 0; k < 256; ++k) {
        const float4 w = wr[k]; const float4 a = hr[k];
        acc += a.x*w.x + a.y*w.y + a.z*w.z + a.w*w.w;
    }
    out0[(size_t)i * 256 + j] = acc + b2[j];
}

// ---------------------------------------------------------------------------
extern "C" void kernel_launch(void* const* d_in, const int* in_sizes, int n_in,
                              void* d_out, int out_size, void* d_ws, size_t ws_size,
                              hipStream_t stream) {
    const float* feat0 = (const float*)d_in[0];
    const float* feat1 = (const float*)d_in[1];
    const float* W1    = (const float*)d_in[2];
    const float* b1    = (const float*)d_in[3];
    const float* gamma = (const float*)d_in[4];
    const float* beta  = (const float*)d_in[5];
    const float* W2    = (const float*)d_in[6];
    const float* b2    = (const float*)d_in[7];
    const float* W3    = (const float*)d_in[8];
    const float* b3    = (const float*)d_in[9];
    const float* W4    = (const float*)d_in[10];
    const float* b4    = (const float*)d_in[11];
    const int* patch_id0 = (const int*)d_in[12];
    const int* patch_id1 = (const int*)d_in[13];
    const int* local_id0 = (const int*)d_in[14];
    const int* local_id1 = (const int*)d_in[15];

    float* out0 = (float*)d_out;                 // (512, 256)
    float* out1 = out0 + 512 * 256;              // (4096, 41, 256)

    float* ws   = (float*)d_ws;
    float* x0m  = ws;                    // 262144 floats
    float* h    = ws + 262144;           // 524288 floats
    float* mu   = ws + 786432;           // 1024
    float* rstd = ws + 787456;           // 1024
    int*   idx  = (int*)(ws + 788480);   // 4096*41 ints
    float* ybuf = ws + 956416;           // 16384*256 floats (per-image, reused)

    const size_t NEED = (size_t)(956416 + 16384 * 256) * sizeof(float); // ~20.6 MB

    if (ws_size >= NEED) {
        // --- new branch-1 pipeline: dedup MLP to per-pixel ---
        k_sims1<<<4096, 128, 0, stream>>>(feat1, patch_id1, local_id1, idx);
        for (int b = 0; b < 8; ++b) {
            k_mlp_pix<<<512, 256, 0, stream>>>(
                feat1 + (size_t)b * 64 * 16384, W3, b3, W4, b4, ybuf);
            k_gather1<<<512, 256, 0, stream>>>(
                ybuf, idx + (size_t)b * 512 * 41,
                out1 + (size_t)b * 512 * 41 * 256);
        }
    } else {
        // --- fallback: verified fused kernel ---
        k_branch1<<<4096, 256, 0, stream>>>(feat1, patch_id1, local_id1,
                                            W3, b3, W4, b4, out1);
    }

    // branch 0 chain
    k_sample0<<<512, 64, 0, stream>>>(feat0, patch_id0, local_id0, x0m);
    k_gemm1<<<dim3(4, 512), 256, 0, stream>>>(x0m, W1, b1, h);
    k_bnstats<<<1024, 64, 0, stream>>>(h, mu, rstd);
    k_bnapply<<<512, 256, 0, stream>>>(h, mu, rstd, gamma, beta);
    k_gemm2<<<512, 256, 0, stream>>>(h, W2, b2, out0);
}

// Round 2
// 1140.638 us; speedup vs baseline: 1.0961x; 1.0961x over previous
//
#include <hip/hip_runtime.h>
#include <math.h>

// ===========================================================================
// Branch-1 pipeline (tiered on workspace size):
//   T) k_transpose1: feat1 (C,HW) -> featT (HW,C) per image, coalesced.
//   A) k_sims1T / k_sims1: per (b,n) fp64 cosine sims + stable top-40 -> ids
//   B) k_mlp_pix: dense MLP (64->256 relu ->256) + L2-norm for ALL pixels.
//   C) k_gather1: out1[bn, mi, :] = ybuf[pix, :]
// Fallback: original fused k_branch1 (verified 1323.6us).
// ===========================================================================

__global__ __launch_bounds__(256) void k_transpose1(
    const float* __restrict__ feat1, float* __restrict__ featT)
{
    __shared__ float tile[64][65];
    const int b = blockIdx.y;
    const int p0 = blockIdx.x * 64;
    const int tid = threadIdx.x;
    const float* fb = feat1 + (size_t)b * 64 * 16384;
    float* ft = featT + (size_t)b * 16384 * 64;
    #pragma unroll
    for (int it = 0; it < 16; ++it) {
        const int e = it * 256 + tid;
        const int c = e >> 6, p = e & 63;      // lanes consecutive in p
        tile[p][c] = fb[(size_t)c * 16384 + p0 + p];
    }
    __syncthreads();
    #pragma unroll
    for (int it = 0; it < 16; ++it) {
        const int e = it * 256 + tid;
        const int p = e >> 6, c = e & 63;      // lanes consecutive in c
        ft[(size_t)(p0 + p) * 64 + c] = tile[p][c];
    }
}

// sims from transposed features: contiguous float4 row reads.
// Accumulation order (c ascending, d then q per element) matches the scalar
// version exactly -> bitwise-identical fp64 sims -> identical ranking.
__global__ __launch_bounds__(128) void k_sims1T(
    const float* __restrict__ featT, const int* __restrict__ patch_id1,
    const int* __restrict__ local_id1, int* __restrict__ idx)
{
    __shared__ float cen[64];
    __shared__ double sims[80];
    __shared__ double cnorm;

    const int row = blockIdx.x;          // 0..4095
    const int b = row >> 9;
    const int n = row & 511;
    const int tid = threadIdx.x;
    const float* ft = featT + (size_t)b * 16384 * 64;
    const int pid = patch_id1[n];
    const int* lids = local_id1 + n * 80;

    if (tid < 64) cen[tid] = ft[(size_t)pid * 64 + tid];
    __syncthreads();

    if (tid < 64) {
        double v = (double)cen[tid];
        double s = v * v;
        for (int o = 32; o > 0; o >>= 1) s += __shfl_down(s, o);
        if (tid == 0) { s = sqrt(s); cnorm = (s < 1e-12) ? 1e-12 : s; }
    }
    __syncthreads();

    if (tid < 80) {
        const float4* rp = (const float4*)(ft + (size_t)lids[tid] * 64);
        double d = 0.0, q = 0.0;
        #pragma unroll
        for (int k = 0; k < 16; ++k) {
            const float4 v4 = rp[k];
            double v;
            v = (double)v4.x; d += v * (double)cen[4*k+0]; q += v*v;
            v = (double)v4.y; d += v * (double)cen[4*k+1]; q += v*v;
            v = (double)v4.z; d += v * (double)cen[4*k+2]; q += v*v;
            v = (double)v4.w; d += v * (double)cen[4*k+3]; q += v*v;
        }
        double nl = sqrt(q); if (nl < 1e-12) nl = 1e-12;
        sims[tid] = d / (nl * cnorm);
    }
    __syncthreads();

    if (tid < 80) {
        const double s = sims[tid];
        int rank = 0;
        for (int j = 0; j < 80; ++j) {
            const double sj = sims[j];
            rank += (sj > s) || (sj == s && j < tid);
        }
        if (rank < 40) idx[row * 41 + 1 + rank] = lids[tid];
    }
    if (tid == 0) idx[row * 41] = pid;
}

// Untransposed sims (tier-1 fallback, verified this session).
__global__ __launch_bounds__(128) void k_sims1(
    const float* __restrict__ feat1, const int* __restrict__ patch_id1,
    const int* __restrict__ local_id1, int* __restrict__ idx)
{
    __shared__ float cen[64];
    __shared__ double sims[80];
    __shared__ double cnorm;

    const int row = blockIdx.x;
    const int b = row >> 9;
    const int n = row & 511;
    const int tid = threadIdx.x;
    const float* fb = feat1 + (size_t)b * 64 * 16384;
    const int pid = patch_id1[n];
    const int* lids = local_id1 + n * 80;

    if (tid < 64) cen[tid] = fb[(size_t)tid * 16384 + pid];
    __syncthreads();

    if (tid < 64) {
        double v = (double)cen[tid];
        double s = v * v;
        for (int o = 32; o > 0; o >>= 1) s += __shfl_down(s, o);
        if (tid == 0) { s = sqrt(s); cnorm = (s < 1e-12) ? 1e-12 : s; }
    }
    __syncthreads();

    if (tid < 80) {
        const int lpix = lids[tid];
        double d = 0.0, q = 0.0;
        for (int c = 0; c < 64; ++c) {
            double v = (double)fb[(size_t)c * 16384 + lpix];
            d += v * (double)cen[c];
            q += v * v;
        }
        double nl = sqrt(q); if (nl < 1e-12) nl = 1e-12;
        sims[tid] = d / (nl * cnorm);
    }
    __syncthreads();

    if (tid < 80) {
        const double s = sims[tid];
        int rank = 0;
        for (int j = 0; j < 80; ++j) {
            const double sj = sims[j];
            rank += (sj > s) || (sj == s && j < tid);
        }
        if (rank < 40) idx[row * 41 + 1 + rank] = lids[tid];
    }
    if (tid == 0) idx[row * 41] = pid;
}

// Dense per-pixel MLP for one image. 32 pixels per block, 256 threads.
__global__ __launch_bounds__(256) void k_mlp_pix(
    const float* __restrict__ fb,       // feat1 + b*64*16384  (C=64, HW=16384)
    const float* __restrict__ W3, const float* __restrict__ b3,
    const float* __restrict__ W4, const float* __restrict__ b4,
    float* __restrict__ ybuf)           // (16384, 256)
{
    __shared__ __align__(16) float xs[32 * 68];
    __shared__ __align__(16) float t1s[32 * 256];

    const int tid = threadIdx.x;
    const int p0 = blockIdx.x * 32;

    {
        const int p = tid & 31;
        const int cg = tid >> 5;
        #pragma unroll
        for (int k = 0; k < 8; ++k) {
            const int c = cg * 8 + k;
            xs[p * 68 + c] = fb[(size_t)c * 16384 + p0 + p];
        }
    }
    __syncthreads();

    const int jg = tid & 63;
    const int g = tid >> 6;
    const int j0 = jg * 4;
    const int mb = g * 8;

    // ---- stage 1: t1 = relu(xs @ W3^T + b3) ----
    {
        float acc[8][4];
        #pragma unroll
        for (int r = 0; r < 8; ++r) {
            acc[r][0] = 0.f; acc[r][1] = 0.f; acc[r][2] = 0.f; acc[r][3] = 0.f;
        }
        const float4* W3f = (const float4*)W3;
        const float4* xsf = (const float4*)xs;
        #pragma unroll 4
        for (int c4 = 0; c4 < 16; ++c4) {
            const float4 w0 = W3f[(j0 + 0) * 16 + c4];
            const float4 w1 = W3f[(j0 + 1) * 16 + c4];
            const float4 w2 = W3f[(j0 + 2) * 16 + c4];
            const float4 w3 = W3f[(j0 + 3) * 16 + c4];
            #pragma unroll
            for (int r = 0; r < 8; ++r) {
                const float4 x4 = xsf[(mb + r) * 17 + c4];
                acc[r][0] += x4.x*w0.x + x4.y*w0.y + x4.z*w0.z + x4.w*w0.w;
                acc[r][1] += x4.x*w1.x + x4.y*w1.y + x4.z*w1.z + x4.w*w1.w;
                acc[r][2] += x4.x*w2.x + x4.y*w2.y + x4.z*w2.z + x4.w*w2.w;
                acc[r][3] += x4.x*w3.x + x4.y*w3.y + x4.z*w3.z + x4.w*w3.w;
            }
        }
        const float bb0 = b3[j0], bb1 = b3[j0+1], bb2 = b3[j0+2], bb3 = b3[j0+3];
        #pragma unroll
        for (int r = 0; r < 8; ++r) {
            float4 o4;
            o4.x = fmaxf(acc[r][0] + bb0, 0.f);
            o4.y = fmaxf(acc[r][1] + bb1, 0.f);
            o4.z = fmaxf(acc[r][2] + bb2, 0.f);
            o4.w = fmaxf(acc[r][3] + bb3, 0.f);
            *(float4*)&t1s[(mb + r) * 256 + j0] = o4;
        }
    }
    __syncthreads();

    // ---- stage 2: y = t1 @ W4^T + b4, L2-normalize, store ----
    {
        float acc[8][4];
        #pragma unroll
        for (int r = 0; r < 8; ++r) {
            acc[r][0] = 0.f; acc[r][1] = 0.f; acc[r][2] = 0.f; acc[r][3] = 0.f;
        }
        const float4* W4f = (const float4*)W4;
        const float4* t1f = (const float4*)t1s;
        #pragma unroll 4
        for (int j4 = 0; j4 < 64; ++j4) {
            const float4 w0 = W4f[(j0 + 0) * 64 + j4];
            const float4 w1 = W4f[(j0 + 1) * 64 + j4];
            const float4 w2 = W4f[(j0 + 2) * 64 + j4];
            const float4 w3 = W4f[(j0 + 3) * 64 + j4];
            #pragma unroll
            for (int r = 0; r < 8; ++r) {
                const float4 t4 = t1f[(mb + r) * 64 + j4];
                acc[r][0] += t4.x*w0.x + t4.y*w0.y + t4.z*w0.z + t4.w*w0.w;
                acc[r][1] += t4.x*w1.x + t4.y*w1.y + t4.z*w1.z + t4.w*w1.w;
                acc[r][2] += t4.x*w2.x + t4.y*w2.y + t4.z*w2.z + t4.w*w2.w;
                acc[r][3] += t4.x*w3.x + t4.y*w3.y + t4.z*w3.z + t4.w*w3.w;
            }
        }
        const float bb0 = b4[j0], bb1 = b4[j0+1], bb2 = b4[j0+2], bb3 = b4[j0+3];
        #pragma unroll
        for (int r = 0; r < 8; ++r) {
            const float y0 = acc[r][0] + bb0;
            const float y1 = acc[r][1] + bb1;
            const float y2 = acc[r][2] + bb2;
            const float y3 = acc[r][3] + bb3;
            float p = y0*y0 + y1*y1 + y2*y2 + y3*y3;
            for (int o = 1; o < 64; o <<= 1) p += __shfl_xor(p, o);
            const float inv = 1.f / (sqrtf(p) + 1e-7f);
            float4 o4 = make_float4(y0*inv, y1*inv, y2*inv, y3*inv);
            *(float4*)&ybuf[(size_t)(p0 + mb + r) * 256 + j0] = o4;
        }
    }
}

__global__ __launch_bounds__(256) void k_gather1(
    const float* __restrict__ ybuf, const int* __restrict__ idxb,
    float* __restrict__ out1b)
{
    __shared__ int pix[41];
    const int n = blockIdx.x;
    const int tid = threadIdx.x;
    if (tid < 41) pix[tid] = idxb[n * 41 + tid];
    __syncthreads();
    const float4* yb4 = (const float4*)ybuf;
    float4* o4 = (float4*)(out1b + (size_t)n * 41 * 256);
    for (int e = tid; e < 41 * 64; e += 256) {
        const int mi = e >> 6, j4 = e & 63;
        o4[mi * 64 + j4] = yb4[pix[mi] * 64 + j4];
    }
}

// ===========================================================================
// FALLBACK: original fused branch-1 kernel (verified)
// ===========================================================================
__global__ __launch_bounds__(256) void k_branch1(
    const float* __restrict__ feat1, const int* __restrict__ patch_id1,
    const int* __restrict__ local_id1, const float* __restrict__ W3,
    const float* __restrict__ b3, const float* __restrict__ W4,
    const float* __restrict__ b4, float* __restrict__ out1)
{
    __shared__ __align__(16) float xs[44 * 64];
    __shared__ __align__(16) float t1s[44 * 256];
    __shared__ double sims[80];
    __shared__ int winners[40];
    __shared__ float cen[64];
    __shared__ double cnorm;

    const int row = blockIdx.x;
    const int b = row >> 9;
    const int n = row & 511;
    const int tid = threadIdx.x;
    const float* fb = feat1 + (size_t)b * 64 * 16384;
    const int pid = patch_id1[n];
    const int* lids = local_id1 + n * 80;

    if (tid < 64) cen[tid] = fb[(size_t)tid * 16384 + pid];
    __syncthreads();

    if (tid < 64) {
        double v = (double)cen[tid];
        double s = v * v;
        for (int o = 32; o > 0; o >>= 1) s += __shfl_down(s, o);
        if (tid == 0) { s = sqrt(s); cnorm = (s < 1e-12) ? 1e-12 : s; }
    }
    __syncthreads();

    if (tid < 80) {
        const int lpix = lids[tid];
        double d = 0.0, q = 0.0;
        for (int c = 0; c < 64; ++c) {
            double v = (double)fb[(size_t)c * 16384 + lpix];
            d += v * (double)cen[c];
            q += v * v;
        }
        double nl = sqrt(q); if (nl < 1e-12) nl = 1e-12;
        sims[tid] = d / (nl * cnorm);
    }
    __syncthreads();

    if (tid < 80) {
        const double s = sims[tid];
        int rank = 0;
        for (int j = 0; j < 80; ++j) {
            const double sj = sims[j];
            rank += (sj > s) || (sj == s && j < tid);
        }
        if (rank < 40) winners[rank] = tid;
    }
    __syncthreads();

    for (int m = tid; m < 44 * 64; m += 256) {
        const int mi = m >> 6, c = m & 63;
        float v;
        if (mi >= 1 && mi <= 40) v = fb[(size_t)c * 16384 + lids[winners[mi - 1]]];
        else v = cen[c];
        xs[m] = v;
    }
    __syncthreads();

    const int jg = tid & 63;
    const int g = tid >> 6;
    const int j0 = jg * 4;
    const int mb = g * 11;

    {
        float acc[11][4];
        #pragma unroll
        for (int r = 0; r < 11; ++r) {
            acc[r][0] = 0.f; acc[r][1] = 0.f; acc[r][2] = 0.f; acc[r][3] = 0.f;
        }
        const float4* W3f = (const float4*)W3;
        const float4* xsf = (const float4*)xs;
        #pragma unroll 4
        for (int c4 = 0; c4 < 16; ++c4) {
            const float4 w0 = W3f[(j0 + 0) * 16 + c4];
            const float4 w1 = W3f[(j0 + 1) * 16 + c4];
            const float4 w2 = W3f[(j0 + 2) * 16 + c4];
            const float4 w3 = W3f[(j0 + 3) * 16 + c4];
            #pragma unroll
            for (int r = 0; r < 11; ++r) {
                const float4 x4 = xsf[(mb + r) * 16 + c4];
                acc[r][0] += x4.x*w0.x + x4.y*w0.y + x4.z*w0.z + x4.w*w0.w;
                acc[r][1] += x4.x*w1.x + x4.y*w1.y + x4.z*w1.z + x4.w*w1.w;
                acc[r][2] += x4.x*w2.x + x4.y*w2.y + x4.z*w2.z + x4.w*w2.w;
                acc[r][3] += x4.x*w3.x + x4.y*w3.y + x4.z*w3.z + x4.w*w3.w;
            }
        }
        const float bb0 = b3[j0], bb1 = b3[j0+1], bb2 = b3[j0+2], bb3 = b3[j0+3];
        #pragma unroll
        for (int r = 0; r < 11; ++r) {
            float4 o4;
            o4.x = fmaxf(acc[r][0] + bb0, 0.f);
            o4.y = fmaxf(acc[r][1] + bb1, 0.f);
            o4.z = fmaxf(acc[r][2] + bb2, 0.f);
            o4.w = fmaxf(acc[r][3] + bb3, 0.f);
            *(float4*)&t1s[(mb + r) * 256 + j0] = o4;
        }
    }
    __syncthreads();

    {
        float acc[11][4];
        #pragma unroll
        for (int r = 0; r < 11; ++r) {
            acc[r][0] = 0.f; acc[r][1] = 0.f; acc[r][2] = 0.f; acc[r][3] = 0.f;
        }
        const float4* W4f = (const float4*)W4;
        const float4* t1f = (const float4*)t1s;
        #pragma unroll 2
        for (int j4 = 0; j4 < 64; ++j4) {
            const float4 w0 = W4f[(j0 + 0) * 64 + j4];
            const float4 w1 = W4f[(j0 + 1) * 64 + j4];
            const float4 w2 = W4f[(j0 + 2) * 64 + j4];
            const float4 w3 = W4f[(j0 + 3) * 64 + j4];
            #pragma unroll
            for (int r = 0; r < 11; ++r) {
                const float4 t4 = t1f[(mb + r) * 64 + j4];
                acc[r][0] += t4.x*w0.x + t4.y*w0.y + t4.z*w0.z + t4.w*w0.w;
                acc[r][1] += t4.x*w1.x + t4.y*w1.y + t4.z*w1.z + t4.w*w1.w;
                acc[r][2] += t4.x*w2.x + t4.y*w2.y + t4.z*w2.z + t4.w*w2.w;
                acc[r][3] += t4.x*w3.x + t4.y*w3.y + t4.z*w3.z + t4.w*w3.w;
            }
        }
        const float bb0 = b4[j0], bb1 = b4[j0+1], bb2 = b4[j0+2], bb3 = b4[j0+3];
        #pragma unroll
        for (int r = 0; r < 11; ++r) {
            const float y0 = acc[r][0] + bb0;
            const float y1 = acc[r][1] + bb1;
            const float y2 = acc[r][2] + bb2;
            const float y3 = acc[r][3] + bb3;
            float p = y0*y0 + y1*y1 + y2*y2 + y3*y3;
            for (int o = 1; o < 64; o <<= 1) p += __shfl_xor(p, o);
            const float inv = 1.f / (sqrtf(p) + 1e-7f);
            const int mi = mb + r;
            if (mi < 41) {
                float4 o4 = make_float4(y0*inv, y1*inv, y2*inv, y3*inv);
                *(float4*)&out1[((size_t)row * 41 + mi) * 256 + j0] = o4;
            }
        }
    }
}

// ---------------------------------------------------------------------------
// Branch 0 kernels
// ---------------------------------------------------------------------------
__global__ __launch_bounds__(64) void k_sample0(
    const float* __restrict__ feat0, const int* __restrict__ patch_id0,
    const int* __restrict__ local_id0, float* __restrict__ x0m)
{
    __shared__ float cen[512];
    __shared__ float loc[8][512];
    __shared__ double sims[8];
    __shared__ int winners[4];
    __shared__ double cnorm;

    const int row = blockIdx.x;
    const int b = row >> 6;
    const int n = row & 63;
    const int t = threadIdx.x;
    const float* fb = feat0 + (size_t)b * 512 * 64;
    const int pid = patch_id0[n];

    for (int c = t; c < 512; c += 64) cen[c] = fb[(size_t)c * 64 + pid];
    for (int l = 0; l < 8; ++l) {
        const int lp = local_id0[n * 8 + l];
        for (int c = t; c < 512; c += 64) loc[l][c] = fb[(size_t)c * 64 + lp];
    }
    __syncthreads();

    double cs = 0.0;
    for (int c = t; c < 512; c += 64) { double v = (double)cen[c]; cs += v * v; }
    for (int o = 32; o > 0; o >>= 1) cs += __shfl_down(cs, o);
    if (t == 0) { cs = sqrt(cs); cnorm = (cs < 1e-12) ? 1e-12 : cs; }
    __syncthreads();

    for (int l = 0; l < 8; ++l) {
        double d = 0.0, q = 0.0;
        for (int c = t; c < 512; c += 64) {
            double v = (double)loc[l][c];
            d += v * (double)cen[c];
            q += v * v;
        }
        for (int o = 32; o > 0; o >>= 1) { d += __shfl_down(d, o); q += __shfl_down(q, o); }
        if (t == 0) {
            double nl = sqrt(q); if (nl < 1e-12) nl = 1e-12;
            sims[l] = d / (nl * cnorm);
        }
    }
    __syncthreads();

    if (t < 8) {
        const double s = sims[t];
        int rank = 0;
        for (int j = 0; j < 8; ++j) {
            const double sj = sims[j];
            rank += (sj > s) || (sj == s && j < t);
        }
        if (rank < 4) winners[rank] = t;
    }
    __syncthreads();

    for (int c = t; c < 512; c += 64) {
        float a = cen[c];
        for (int r = 0; r < 4; ++r) a += loc[winners[r]][c];
        x0m[(size_t)row * 512 + c] = a * 0.2f;
    }
}

// Tiled GEMM1: h = x @ W1^T + b1.  M=512, N=1024, K=512.
// grid (2 col-halves, 64 row-tiles), 128 threads: block = 8 rows x 512 cols,
// thread = 8 rows x 4 cols. W1 traffic: 1GB -> 128MB vs old version.
__global__ __launch_bounds__(128) void k_gemm1(
    const float* __restrict__ x, const float* __restrict__ W1,
    const float* __restrict__ b1, float* __restrict__ h)
{
    __shared__ __align__(16) float xsr[8 * 512];
    const int i0 = blockIdx.y * 8;
    const int tid = threadIdx.x;
    const int j0 = blockIdx.x * 512 + tid * 4;

    const float4* xg = (const float4*)(x + (size_t)i0 * 512);
    float4* xl = (float4*)xsr;
    #pragma unroll
    for (int e = 0; e < 8; ++e) xl[e * 128 + tid] = xg[e * 128 + tid];
    __syncthreads();

    float acc[8][4];
    #pragma unroll
    for (int r = 0; r < 8; ++r) {
        acc[r][0] = 0.f; acc[r][1] = 0.f; acc[r][2] = 0.f; acc[r][3] = 0.f;
    }
    const float4* W1f = (const float4*)W1;     // row j: W1f[j*128 + c4]
    const float4* xf  = (const float4*)xsr;    // row r: xf[r*128 + c4]
    #pragma unroll 4
    for (int c4 = 0; c4 < 128; ++c4) {
        const float4 w0 = W1f[(size_t)(j0 + 0) * 128 + c4];
        const float4 w1 = W1f[(size_t)(j0 + 1) * 128 + c4];
        const float4 w2 = W1f[(size_t)(j0 + 2) * 128 + c4];
        const float4 w3 = W1f[(size_t)(j0 + 3) * 128 + c4];
        #pragma unroll
        for (int r = 0; r < 8; ++r) {
            const float4 x4 = xf[r * 128 + c4];   // LDS broadcast
            acc[r][0] += x4.x*w0.x + x4.y*w0.y + x4.z*w0.z + x4.w*w0.w;
            acc[r][1] += x4.x*w1.x + x4.y*w1.y + x4.z*w1.z + x4.w*w1.w;
            acc[r][2] += x4.x*w2.x + x4.y*w2.y + x4.z*w2.z + x4.w*w2.w;
            acc[r][3] += x4.x*w3.x + x4.y*w3.y + x4.z*w3.z + x4.w*w3.w;
        }
    }
    const float bb0 = b1[j0], bb1 = b1[j0+1], bb2 = b1[j0+2], bb3 = b1[j0+3];
    #pragma unroll
    for (int r = 0; r < 8; ++r) {
        float4 o4 = make_float4(acc[r][0] + bb0, acc[r][1] + bb1,
                                acc[r][2] + bb2, acc[r][3] + bb3);
        *(float4*)&h[(size_t)(i0 + r) * 1024 + j0] = o4;
    }
}

__global__ __launch_bounds__(64) void k_bnstats(
    const float* __restrict__ h, float* __restrict__ mu, float* __restrict__ rstd)
{
    const int j = blockIdx.x;
    const int t = threadIdx.x;
    float s = 0.f, ss = 0.f;
    for (int i = t; i < 512; i += 64) {
        const float v = h[(size_t)i * 1024 + j];
        s += v; ss += v * v;
    }
    for (int o = 32; o > 0; o >>= 1) { s += __shfl_down(s, o); ss += __shfl_down(ss, o); }
    if (t == 0) {
        const float m = s * (1.f / 512.f);
        const float var = ss * (1.f / 512.f) - m * m;
        mu[j] = m;
        rstd[j] = rsqrtf(var + 1e-5f);
    }
}

__global__ __launch_bounds__(256) void k_bnapply(
    float* __restrict__ h, const float* __restrict__ mu, const float* __restrict__ rstd,
    const float* __restrict__ gamma, const float* __restrict__ beta)
{
    const int e = blockIdx.x * 256 + threadIdx.x;
    const int jb = (e & 255) * 4;
    float4 v = ((float4*)h)[e];
    v.x = fmaxf((v.x - mu[jb+0]) * rstd[jb+0] * gamma[jb+0] + beta[jb+0], 0.f);
    v.y = fmaxf((v.y - mu[jb+1]) * rstd[jb+1] * gamma[jb+1] + beta[jb+1], 0.f);
    v.z = fmaxf((v.z - mu[jb+2]) * rstd[jb+2] * gamma[jb+2] + beta[jb+2], 0.f);
    v.w = fmaxf((v.w - mu[jb+3]) * rstd[jb+3] * gamma[jb+3] + beta[jb+3], 0.f);
    ((float4*)h)[e] = v;
}

// Tiled GEMM2: out0 = relu_h @ W2^T + b2.  M=512, N=256, K=1024.
// grid 64 row-tiles, 256 threads: block = 8 rows x 256 cols, thread = 8 rows
// x 1 col. W2 traffic: 512MB -> 64MB vs old version.
__global__ __launch_bounds__(256) void k_gemm2(
    const float* __restrict__ h, const float* __restrict__ W2,
    const float* __restrict__ b2, float* __restrict__ out0)
{
    __shared__ __align__(16) float hs[8 * 1024];
    const int i0 = blockIdx.x * 8;
    const int j = threadIdx.x;

    const float4* hg = (const float4*)(h + (size_t)i0 * 1024);
    float4* hl = (float4*)hs;
    #pragma unroll
    for (int e = 0; e < 8; ++e) hl[e * 256 + j] = hg[e * 256 + j];
    __syncthreads();

    float acc[8];
    #pragma unroll
    for (int r = 0; r < 8; ++r) acc[r] = 0.f;
    const float4* wr = (const float4*)(W2 + (size_t)j * 1024);
    const float4* hf = (const float4*)hs;
    #pragma unroll 4
    for (int k4 = 0; k4 < 256; ++k4) {
        const float4 w = wr[k4];
        #pragma unroll
        for (int r = 0; r < 8; ++r) {
            const float4 a = hf[r * 256 + k4];    // LDS broadcast
            acc[r] += a.x*w.x + a.y*w.y + a.z*w.z + a.w*w.w;
        }
    }
    const float bb = b2[j];
    #pragma unroll
    for (int r = 0; r < 8; ++r)
        out0[(size_t)(i0 + r) * 256 + j] = acc[r] + bb;
}

// ---------------------------------------------------------------------------
extern "C" void kernel_launch(void* const* d_in, const int* in_sizes, int n_in,
                              void* d_out, int out_size, void* d_ws, size_t ws_size,
                              hipStream_t stream) {
    const float* feat0 = (const float*)d_in[0];
    const float* feat1 = (const float*)d_in[1];
    const float* W1    = (const float*)d_in[2];
    const float* b1    = (const float*)d_in[3];
    const float* gamma = (const float*)d_in[4];
    const float* beta  = (const float*)d_in[5];
    const float* W2    = (const float*)d_in[6];
    const float* b2    = (const float*)d_in[7];
    const float* W3    = (const float*)d_in[8];
    const float* b3    = (const float*)d_in[9];
    const float* W4    = (const float*)d_in[10];
    const float* b4    = (const float*)d_in[11];
    const int* patch_id0 = (const int*)d_in[12];
    const int* patch_id1 = (const int*)d_in[13];
    const int* local_id0 = (const int*)d_in[14];
    const int* local_id1 = (const int*)d_in[15];

    float* out0 = (float*)d_out;                 // (512, 256)
    float* out1 = out0 + 512 * 256;              // (4096, 41, 256)

    float* ws    = (float*)d_ws;
    float* x0m   = ws;                    // 262144 floats
    float* h     = ws + 262144;           // 524288 floats
    float* mu    = ws + 786432;           // 1024
    float* rstd  = ws + 787456;           // 1024
    int*   idx   = (int*)(ws + 788480);   // 4096*41 ints -> 167936 slots
    float* ybuf  = ws + 956416;           // 16384*256 floats (per-image, reused)
    float* featT = ws + 5150720;          // 8*16384*64 floats

    const size_t NEED1 = (size_t)5150720 * 4 + (size_t)4194304 * 4;   // ~20.6 MB... (ybuf end)
    const size_t NEED1b = (size_t)(956416 + 4194304) * 4;             // = 20602880
    const size_t NEED2  = (size_t)(5150720 + 8388608) * 4;            // = 54157312
    (void)NEED1;

    if (ws_size >= NEED1b) {
        if (ws_size >= NEED2) {
            k_transpose1<<<dim3(256, 8), 256, 0, stream>>>(feat1, featT);
            k_sims1T<<<4096, 128, 0, stream>>>(featT, patch_id1, local_id1, idx);
        } else {
            k_sims1<<<4096, 128, 0, stream>>>(feat1, patch_id1, local_id1, idx);
        }
        for (int b = 0; b < 8; ++b) {
            k_mlp_pix<<<512, 256, 0, stream>>>(
                feat1 + (size_t)b * 64 * 16384, W3, b3, W4, b4, ybuf);
            k_gather1<<<512, 256, 0, stream>>>(
                ybuf, idx + (size_t)b * 512 * 41,
                out1 + (size_t)b * 512 * 41 * 256);
        }
    } else {
        k_branch1<<<4096, 256, 0, stream>>>(feat1, patch_id1, local_id1,
                                            W3, b3, W4, b4, out1);
    }

    // branch 0 chain
    k_sample0<<<512, 64, 0, stream>>>(feat0, patch_id0, local_id0, x0m);
    k_gemm1<<<dim3(2, 64), 128, 0, stream>>>(x0m, W1, b1, h);
    k_bnstats<<<1024, 64, 0, stream>>>(h, mu, rstd);
    k_bnapply<<<512, 256, 0, stream>>>(h, mu, rstd, gamma, beta);
    k_gemm2<<<64, 256, 0, stream>>>(h, W2, b2, out0);
}

// Round 3
// 796.177 us; speedup vs baseline: 1.5703x; 1.4326x over previous
//
#include <hip/hip_runtime.h>
#include <math.h>

// ===========================================================================
// Branch-1 pipeline (tiered on workspace size):
//   W) k_wtrans:     W3 -> W3T (64x256), W4 -> W4T (256x256), one-time.
//   T) k_transpose1: feat1 (C,HW) -> featT (HW,C) per image, coalesced.
//   A) k_sims1T / k_sims1: per (b,n) fp64 cosine sims + stable top-40 -> ids
//   B) k_mlp_pix2: dense MLP (64->256 relu ->256) + L2-norm for ALL pixels,
//      COALESCED weight loads via W3T/W4T + LDS-broadcast activations.
//   C) k_gather1: out1[bn, mi, :] = ybuf[img, pix, :]
// Fallback: original fused k_branch1 (verified 1323.6us).
// ===========================================================================

__global__ __launch_bounds__(256) void k_wtrans(
    const float* __restrict__ W3, const float* __restrict__ W4,
    float* __restrict__ W3T, float* __restrict__ W4T)
{
    const int t = threadIdx.x;          // 0..255
    const int j = blockIdx.x;           // 0..255
    // W4T[k][j] = W4[j][k]; read row j coalesced over k=t
    W4T[(size_t)t * 256 + j] = W4[(size_t)j * 256 + t];
    if (j < 64) {
        // W3T[c][jj] = W3[jj][c], c = j, jj = t
        W3T[(size_t)j * 256 + t] = W3[(size_t)t * 64 + j];
    }
}

__global__ __launch_bounds__(256) void k_transpose1(
    const float* __restrict__ feat1, float* __restrict__ featT)
{
    __shared__ float tile[64][65];
    const int b = blockIdx.y;
    const int p0 = blockIdx.x * 64;
    const int tid = threadIdx.x;
    const float* fb = feat1 + (size_t)b * 64 * 16384;
    float* ft = featT + (size_t)b * 16384 * 64;
    #pragma unroll
    for (int it = 0; it < 16; ++it) {
        const int e = it * 256 + tid;
        const int c = e >> 6, p = e & 63;
        tile[p][c] = fb[(size_t)c * 16384 + p0 + p];
    }
    __syncthreads();
    #pragma unroll
    for (int it = 0; it < 16; ++it) {
        const int e = it * 256 + tid;
        const int p = e >> 6, c = e & 63;
        ft[(size_t)(p0 + p) * 64 + c] = tile[p][c];
    }
}

// sims from transposed features: contiguous float4 row reads.
__global__ __launch_bounds__(128) void k_sims1T(
    const float* __restrict__ featT, const int* __restrict__ patch_id1,
    const int* __restrict__ local_id1, int* __restrict__ idx)
{
    __shared__ float cen[64];
    __shared__ double sims[80];
    __shared__ double cnorm;

    const int row = blockIdx.x;          // 0..4095
    const int b = row >> 9;
    const int n = row & 511;
    const int tid = threadIdx.x;
    const float* ft = featT + (size_t)b * 16384 * 64;
    const int pid = patch_id1[n];
    const int* lids = local_id1 + n * 80;

    if (tid < 64) cen[tid] = ft[(size_t)pid * 64 + tid];
    __syncthreads();

    if (tid < 64) {
        double v = (double)cen[tid];
        double s = v * v;
        for (int o = 32; o > 0; o >>= 1) s += __shfl_down(s, o);
        if (tid == 0) { s = sqrt(s); cnorm = (s < 1e-12) ? 1e-12 : s; }
    }
    __syncthreads();

    if (tid < 80) {
        const float4* rp = (const float4*)(ft + (size_t)lids[tid] * 64);
        double d = 0.0, q = 0.0;
        #pragma unroll
        for (int k = 0; k < 16; ++k) {
            const float4 v4 = rp[k];
            double v;
            v = (double)v4.x; d += v * (double)cen[4*k+0]; q += v*v;
            v = (double)v4.y; d += v * (double)cen[4*k+1]; q += v*v;
            v = (double)v4.z; d += v * (double)cen[4*k+2]; q += v*v;
            v = (double)v4.w; d += v * (double)cen[4*k+3]; q += v*v;
        }
        double nl = sqrt(q); if (nl < 1e-12) nl = 1e-12;
        sims[tid] = d / (nl * cnorm);
    }
    __syncthreads();

    if (tid < 80) {
        const double s = sims[tid];
        int rank = 0;
        for (int j = 0; j < 80; ++j) {
            const double sj = sims[j];
            rank += (sj > s) || (sj == s && j < tid);
        }
        if (rank < 40) idx[row * 41 + 1 + rank] = lids[tid];
    }
    if (tid == 0) idx[row * 41] = pid;
}

// Untransposed sims (small-ws fallback, verified).
__global__ __launch_bounds__(128) void k_sims1(
    const float* __restrict__ feat1, const int* __restrict__ patch_id1,
    const int* __restrict__ local_id1, int* __restrict__ idx)
{
    __shared__ float cen[64];
    __shared__ double sims[80];
    __shared__ double cnorm;

    const int row = blockIdx.x;
    const int b = row >> 9;
    const int n = row & 511;
    const int tid = threadIdx.x;
    const float* fb = feat1 + (size_t)b * 64 * 16384;
    const int pid = patch_id1[n];
    const int* lids = local_id1 + n * 80;

    if (tid < 64) cen[tid] = fb[(size_t)tid * 16384 + pid];
    __syncthreads();

    if (tid < 64) {
        double v = (double)cen[tid];
        double s = v * v;
        for (int o = 32; o > 0; o >>= 1) s += __shfl_down(s, o);
        if (tid == 0) { s = sqrt(s); cnorm = (s < 1e-12) ? 1e-12 : s; }
    }
    __syncthreads();

    if (tid < 80) {
        const int lpix = lids[tid];
        double d = 0.0, q = 0.0;
        for (int c = 0; c < 64; ++c) {
            double v = (double)fb[(size_t)c * 16384 + lpix];
            d += v * (double)cen[c];
            q += v * v;
        }
        double nl = sqrt(q); if (nl < 1e-12) nl = 1e-12;
        sims[tid] = d / (nl * cnorm);
    }
    __syncthreads();

    if (tid < 80) {
        const double s = sims[tid];
        int rank = 0;
        for (int j = 0; j < 80; ++j) {
            const double sj = sims[j];
            rank += (sj > s) || (sj == s && j < tid);
        }
        if (rank < 40) idx[row * 41 + 1 + rank] = lids[tid];
    }
    if (tid == 0) idx[row * 41] = pid;
}

// Dense per-pixel MLP, coalesced-weight version. 32 pixels/block, 256 thr.
// Grid may span several images: img = blockIdx.x >> 9.
// Weight loads: Wf[k*64 + jg] -> 64 consecutive float4s per wave (1KB,
// coalesced). Activations: LDS broadcast (same addr across lanes).
// FP accumulation order identical to the verified per-row version.
__global__ __launch_bounds__(256) void k_mlp_pix2(
    const float* __restrict__ featb,
    const float* __restrict__ W3T, const float* __restrict__ b3,
    const float* __restrict__ W4T, const float* __restrict__ b4,
    float* __restrict__ ybuf, int ybufStride)
{
    __shared__ __align__(16) float xs[32 * 68];
    __shared__ __align__(16) float t1s[32 * 256];

    const int tid = threadIdx.x;
    const int blk = blockIdx.x;
    const int img = blk >> 9;
    const int p0 = (blk & 511) * 32;
    const float* fb = featb + (size_t)img * 64 * 16384;
    float* yb = ybuf + (size_t)img * (size_t)ybufStride;

    {
        const int p = tid & 31;
        const int cg = tid >> 5;
        #pragma unroll
        for (int k = 0; k < 8; ++k) {
            const int c = cg * 8 + k;
            xs[p * 68 + c] = fb[(size_t)c * 16384 + p0 + p];
        }
    }
    __syncthreads();

    const int jg = tid & 63;
    const int g = tid >> 6;
    const int j0 = jg * 4;
    const int mb = g * 8;

    // ---- stage 1: t1 = relu(xs @ W3^T + b3), via W3T coalesced ----
    {
        float acc[8][4];
        #pragma unroll
        for (int r = 0; r < 8; ++r) {
            acc[r][0] = 0.f; acc[r][1] = 0.f; acc[r][2] = 0.f; acc[r][3] = 0.f;
        }
        const float4* Wf = (const float4*)W3T;   // [c][j]: Wf[c*64 + jg]
        const float4* xsf = (const float4*)xs;
        #pragma unroll 4
        for (int cq = 0; cq < 16; ++cq) {
            const float4 wA = Wf[(cq * 4 + 0) * 64 + jg];
            const float4 wB = Wf[(cq * 4 + 1) * 64 + jg];
            const float4 wC = Wf[(cq * 4 + 2) * 64 + jg];
            const float4 wD = Wf[(cq * 4 + 3) * 64 + jg];
            #pragma unroll
            for (int r = 0; r < 8; ++r) {
                const float4 x4 = xsf[(mb + r) * 17 + cq];   // broadcast
                acc[r][0] += x4.x*wA.x + x4.y*wB.x + x4.z*wC.x + x4.w*wD.x;
                acc[r][1] += x4.x*wA.y + x4.y*wB.y + x4.z*wC.y + x4.w*wD.y;
                acc[r][2] += x4.x*wA.z + x4.y*wB.z + x4.z*wC.z + x4.w*wD.z;
                acc[r][3] += x4.x*wA.w + x4.y*wB.w + x4.z*wC.w + x4.w*wD.w;
            }
        }
        const float bb0 = b3[j0], bb1 = b3[j0+1], bb2 = b3[j0+2], bb3 = b3[j0+3];
        #pragma unroll
        for (int r = 0; r < 8; ++r) {
            float4 o4;
            o4.x = fmaxf(acc[r][0] + bb0, 0.f);
            o4.y = fmaxf(acc[r][1] + bb1, 0.f);
            o4.z = fmaxf(acc[r][2] + bb2, 0.f);
            o4.w = fmaxf(acc[r][3] + bb3, 0.f);
            *(float4*)&t1s[(mb + r) * 256 + j0] = o4;
        }
    }
    __syncthreads();

    // ---- stage 2: y = t1 @ W4^T + b4 via W4T coalesced, L2-norm, store ----
    {
        float acc[8][4];
        #pragma unroll
        for (int r = 0; r < 8; ++r) {
            acc[r][0] = 0.f; acc[r][1] = 0.f; acc[r][2] = 0.f; acc[r][3] = 0.f;
        }
        const float4* Wf = (const float4*)W4T;   // [k][j]: Wf[k*64 + jg]
        const float4* t1f = (const float4*)t1s;
        #pragma unroll 2
        for (int kq = 0; kq < 64; ++kq) {
            const float4 wA = Wf[(kq * 4 + 0) * 64 + jg];
            const float4 wB = Wf[(kq * 4 + 1) * 64 + jg];
            const float4 wC = Wf[(kq * 4 + 2) * 64 + jg];
            const float4 wD = Wf[(kq * 4 + 3) * 64 + jg];
            #pragma unroll
            for (int r = 0; r < 8; ++r) {
                const float4 t4 = t1f[(mb + r) * 64 + kq];   // broadcast
                acc[r][0] += t4.x*wA.x + t4.y*wB.x + t4.z*wC.x + t4.w*wD.x;
                acc[r][1] += t4.x*wA.y + t4.y*wB.y + t4.z*wC.y + t4.w*wD.y;
                acc[r][2] += t4.x*wA.z + t4.y*wB.z + t4.z*wC.z + t4.w*wD.z;
                acc[r][3] += t4.x*wA.w + t4.y*wB.w + t4.z*wC.w + t4.w*wD.w;
            }
        }
        const float bb0 = b4[j0], bb1 = b4[j0+1], bb2 = b4[j0+2], bb3 = b4[j0+3];
        #pragma unroll
        for (int r = 0; r < 8; ++r) {
            const float y0 = acc[r][0] + bb0;
            const float y1 = acc[r][1] + bb1;
            const float y2 = acc[r][2] + bb2;
            const float y3 = acc[r][3] + bb3;
            float p = y0*y0 + y1*y1 + y2*y2 + y3*y3;
            for (int o = 1; o < 64; o <<= 1) p += __shfl_xor(p, o);
            const float inv = 1.f / (sqrtf(p) + 1e-7f);
            float4 o4 = make_float4(y0*inv, y1*inv, y2*inv, y3*inv);
            *(float4*)&yb[(size_t)(p0 + mb + r) * 256 + j0] = o4;
        }
    }
}

// Gather normalized rows into out1. Grid may span several images.
__global__ __launch_bounds__(256) void k_gather1(
    const float* __restrict__ ybuf, int ybufStride,
    const int* __restrict__ idxb, float* __restrict__ out1b)
{
    __shared__ int pix[41];
    const int bn = blockIdx.x;
    const int img = bn >> 9;
    const int tid = threadIdx.x;
    if (tid < 41) pix[tid] = idxb[bn * 41 + tid];
    __syncthreads();
    const float4* yb4 = (const float4*)(ybuf + (size_t)img * (size_t)ybufStride);
    float4* o4 = (float4*)(out1b + (size_t)bn * 41 * 256);
    for (int e = tid; e < 41 * 64; e += 256) {
        const int mi = e >> 6, j4 = e & 63;
        o4[mi * 64 + j4] = yb4[pix[mi] * 64 + j4];
    }
}

// ===========================================================================
// FALLBACK: original fused branch-1 kernel (verified)
// ===========================================================================
__global__ __launch_bounds__(256) void k_branch1(
    const float* __restrict__ feat1, const int* __restrict__ patch_id1,
    const int* __restrict__ local_id1, const float* __restrict__ W3,
    const float* __restrict__ b3, const float* __restrict__ W4,
    const float* __restrict__ b4, float* __restrict__ out1)
{
    __shared__ __align__(16) float xs[44 * 64];
    __shared__ __align__(16) float t1s[44 * 256];
    __shared__ double sims[80];
    __shared__ int winners[40];
    __shared__ float cen[64];
    __shared__ double cnorm;

    const int row = blockIdx.x;
    const int b = row >> 9;
    const int n = row & 511;
    const int tid = threadIdx.x;
    const float* fb = feat1 + (size_t)b * 64 * 16384;
    const int pid = patch_id1[n];
    const int* lids = local_id1 + n * 80;

    if (tid < 64) cen[tid] = fb[(size_t)tid * 16384 + pid];
    __syncthreads();

    if (tid < 64) {
        double v = (double)cen[tid];
        double s = v * v;
        for (int o = 32; o > 0; o >>= 1) s += __shfl_down(s, o);
        if (tid == 0) { s = sqrt(s); cnorm = (s < 1e-12) ? 1e-12 : s; }
    }
    __syncthreads();

    if (tid < 80) {
        const int lpix = lids[tid];
        double d = 0.0, q = 0.0;
        for (int c = 0; c < 64; ++c) {
            double v = (double)fb[(size_t)c * 16384 + lpix];
            d += v * (double)cen[c];
            q += v * v;
        }
        double nl = sqrt(q); if (nl < 1e-12) nl = 1e-12;
        sims[tid] = d / (nl * cnorm);
    }
    __syncthreads();

    if (tid < 80) {
        const double s = sims[tid];
        int rank = 0;
        for (int j = 0; j < 80; ++j) {
            const double sj = sims[j];
            rank += (sj > s) || (sj == s && j < tid);
        }
        if (rank < 40) winners[rank] = tid;
    }
    __syncthreads();

    for (int m = tid; m < 44 * 64; m += 256) {
        const int mi = m >> 6, c = m & 63;
        float v;
        if (mi >= 1 && mi <= 40) v = fb[(size_t)c * 16384 + lids[winners[mi - 1]]];
        else v = cen[c];
        xs[m] = v;
    }
    __syncthreads();

    const int jg = tid & 63;
    const int g = tid >> 6;
    const int j0 = jg * 4;
    const int mb = g * 11;

    {
        float acc[11][4];
        #pragma unroll
        for (int r = 0; r < 11; ++r) {
            acc[r][0] = 0.f; acc[r][1] = 0.f; acc[r][2] = 0.f; acc[r][3] = 0.f;
        }
        const float4* W3f = (const float4*)W3;
        const float4* xsf = (const float4*)xs;
        #pragma unroll 4
        for (int c4 = 0; c4 < 16; ++c4) {
            const float4 w0 = W3f[(j0 + 0) * 16 + c4];
            const float4 w1 = W3f[(j0 + 1) * 16 + c4];
            const float4 w2 = W3f[(j0 + 2) * 16 + c4];
            const float4 w3 = W3f[(j0 + 3) * 16 + c4];
            #pragma unroll
            for (int r = 0; r < 11; ++r) {
                const float4 x4 = xsf[(mb + r) * 16 + c4];
                acc[r][0] += x4.x*w0.x + x4.y*w0.y + x4.z*w0.z + x4.w*w0.w;
                acc[r][1] += x4.x*w1.x + x4.y*w1.y + x4.z*w1.z + x4.w*w1.w;
                acc[r][2] += x4.x*w2.x + x4.y*w2.y + x4.z*w2.z + x4.w*w2.w;
                acc[r][3] += x4.x*w3.x + x4.y*w3.y + x4.z*w3.z + x4.w*w3.w;
            }
        }
        const float bb0 = b3[j0], bb1 = b3[j0+1], bb2 = b3[j0+2], bb3 = b3[j0+3];
        #pragma unroll
        for (int r = 0; r < 11; ++r) {
            float4 o4;
            o4.x = fmaxf(acc[r][0] + bb0, 0.f);
            o4.y = fmaxf(acc[r][1] + bb1, 0.f);
            o4.z = fmaxf(acc[r][2] + bb2, 0.f);
            o4.w = fmaxf(acc[r][3] + bb3, 0.f);
            *(float4*)&t1s[(mb + r) * 256 + j0] = o4;
        }
    }
    __syncthreads();

    {
        float acc[11][4];
        #pragma unroll
        for (int r = 0; r < 11; ++r) {
            acc[r][0] = 0.f; acc[r][1] = 0.f; acc[r][2] = 0.f; acc[r][3] = 0.f;
        }
        const float4* W4f = (const float4*)W4;
        const float4* t1f = (const float4*)t1s;
        #pragma unroll 2
        for (int j4 = 0; j4 < 64; ++j4) {
            const float4 w0 = W4f[(j0 + 0) * 64 + j4];
            const float4 w1 = W4f[(j0 + 1) * 64 + j4];
            const float4 w2 = W4f[(j0 + 2) * 64 + j4];
            const float4 w3 = W4f[(j0 + 3) * 64 + j4];
            #pragma unroll
            for (int r = 0; r < 11; ++r) {
                const float4 t4 = t1f[(mb + r) * 64 + j4];
                acc[r][0] += t4.x*w0.x + t4.y*w0.y + t4.z*w0.z + t4.w*w0.w;
                acc[r][1] += t4.x*w1.x + t4.y*w1.y + t4.z*w1.z + t4.w*w1.w;
                acc[r][2] += t4.x*w2.x + t4.y*w2.y + t4.z*w2.z + t4.w*w2.w;
                acc[r][3] += t4.x*w3.x + t4.y*w3.y + t4.z*w3.z + t4.w*w3.w;
            }
        }
        const float bb0 = b4[j0], bb1 = b4[j0+1], bb2 = b4[j0+2], bb3 = b4[j0+3];
        #pragma unroll
        for (int r = 0; r < 11; ++r) {
            const float y0 = acc[r][0] + bb0;
            const float y1 = acc[r][1] + bb1;
            const float y2 = acc[r][2] + bb2;
            const float y3 = acc[r][3] + bb3;
            float p = y0*y0 + y1*y1 + y2*y2 + y3*y3;
            for (int o = 1; o < 64; o <<= 1) p += __shfl_xor(p, o);
            const float inv = 1.f / (sqrtf(p) + 1e-7f);
            const int mi = mb + r;
            if (mi < 41) {
                float4 o4 = make_float4(y0*inv, y1*inv, y2*inv, y3*inv);
                *(float4*)&out1[((size_t)row * 41 + mi) * 256 + j0] = o4;
            }
        }
    }
}

// ---------------------------------------------------------------------------
// Branch 0 kernels
// ---------------------------------------------------------------------------
__global__ __launch_bounds__(64) void k_sample0(
    const float* __restrict__ feat0, const int* __restrict__ patch_id0,
    const int* __restrict__ local_id0, float* __restrict__ x0m)
{
    __shared__ float cen[512];
    __shared__ float loc[8][512];
    __shared__ double sims[8];
    __shared__ int winners[4];
    __shared__ double cnorm;

    const int row = blockIdx.x;
    const int b = row >> 6;
    const int n = row & 63;
    const int t = threadIdx.x;
    const float* fb = feat0 + (size_t)b * 512 * 64;
    const int pid = patch_id0[n];

    for (int c = t; c < 512; c += 64) cen[c] = fb[(size_t)c * 64 + pid];
    for (int l = 0; l < 8; ++l) {
        const int lp = local_id0[n * 8 + l];
        for (int c = t; c < 512; c += 64) loc[l][c] = fb[(size_t)c * 64 + lp];
    }
    __syncthreads();

    double cs = 0.0;
    for (int c = t; c < 512; c += 64) { double v = (double)cen[c]; cs += v * v; }
    for (int o = 32; o > 0; o >>= 1) cs += __shfl_down(cs, o);
    if (t == 0) { cs = sqrt(cs); cnorm = (cs < 1e-12) ? 1e-12 : cs; }
    __syncthreads();

    for (int l = 0; l < 8; ++l) {
        double d = 0.0, q = 0.0;
        for (int c = t; c < 512; c += 64) {
            double v = (double)loc[l][c];
            d += v * (double)cen[c];
            q += v * v;
        }
        for (int o = 32; o > 0; o >>= 1) { d += __shfl_down(d, o); q += __shfl_down(q, o); }
        if (t == 0) {
            double nl = sqrt(q); if (nl < 1e-12) nl = 1e-12;
            sims[l] = d / (nl * cnorm);
        }
    }
    __syncthreads();

    if (t < 8) {
        const double s = sims[t];
        int rank = 0;
        for (int j = 0; j < 8; ++j) {
            const double sj = sims[j];
            rank += (sj > s) || (sj == s && j < t);
        }
        if (rank < 4) winners[rank] = t;
    }
    __syncthreads();

    for (int c = t; c < 512; c += 64) {
        float a = cen[c];
        for (int r = 0; r < 4; ++r) a += loc[winners[r]][c];
        x0m[(size_t)row * 512 + c] = a * 0.2f;
    }
}

__global__ __launch_bounds__(128) void k_gemm1(
    const float* __restrict__ x, const float* __restrict__ W1,
    const float* __restrict__ b1, float* __restrict__ h)
{
    __shared__ __align__(16) float xsr[8 * 512];
    const int i0 = blockIdx.y * 8;
    const int tid = threadIdx.x;
    const int j0 = blockIdx.x * 512 + tid * 4;

    const float4* xg = (const float4*)(x + (size_t)i0 * 512);
    float4* xl = (float4*)xsr;
    #pragma unroll
    for (int e = 0; e < 8; ++e) xl[e * 128 + tid] = xg[e * 128 + tid];
    __syncthreads();

    float acc[8][4];
    #pragma unroll
    for (int r = 0; r < 8; ++r) {
        acc[r][0] = 0.f; acc[r][1] = 0.f; acc[r][2] = 0.f; acc[r][3] = 0.f;
    }
    const float4* W1f = (const float4*)W1;
    const float4* xf  = (const float4*)xsr;
    #pragma unroll 4
    for (int c4 = 0; c4 < 128; ++c4) {
        const float4 w0 = W1f[(size_t)(j0 + 0) * 128 + c4];
        const float4 w1 = W1f[(size_t)(j0 + 1) * 128 + c4];
        const float4 w2 = W1f[(size_t)(j0 + 2) * 128 + c4];
        const float4 w3 = W1f[(size_t)(j0 + 3) * 128 + c4];
        #pragma unroll
        for (int r = 0; r < 8; ++r) {
            const float4 x4 = xf[r * 128 + c4];
            acc[r][0] += x4.x*w0.x + x4.y*w0.y + x4.z*w0.z + x4.w*w0.w;
            acc[r][1] += x4.x*w1.x + x4.y*w1.y + x4.z*w1.z + x4.w*w1.w;
            acc[r][2] += x4.x*w2.x + x4.y*w2.y + x4.z*w2.z + x4.w*w2.w;
            acc[r][3] += x4.x*w3.x + x4.y*w3.y + x4.z*w3.z + x4.w*w3.w;
        }
    }
    const float bb0 = b1[j0], bb1 = b1[j0+1], bb2 = b1[j0+2], bb3 = b1[j0+3];
    #pragma unroll
    for (int r = 0; r < 8; ++r) {
        float4 o4 = make_float4(acc[r][0] + bb0, acc[r][1] + bb1,
                                acc[r][2] + bb2, acc[r][3] + bb3);
        *(float4*)&h[(size_t)(i0 + r) * 1024 + j0] = o4;
    }
}

__global__ __launch_bounds__(64) void k_bnstats(
    const float* __restrict__ h, float* __restrict__ mu, float* __restrict__ rstd)
{
    const int j = blockIdx.x;
    const int t = threadIdx.x;
    float s = 0.f, ss = 0.f;
    for (int i = t; i < 512; i += 64) {
        const float v = h[(size_t)i * 1024 + j];
        s += v; ss += v * v;
    }
    for (int o = 32; o > 0; o >>= 1) { s += __shfl_down(s, o); ss += __shfl_down(ss, o); }
    if (t == 0) {
        const float m = s * (1.f / 512.f);
        const float var = ss * (1.f / 512.f) - m * m;
        mu[j] = m;
        rstd[j] = rsqrtf(var + 1e-5f);
    }
}

__global__ __launch_bounds__(256) void k_bnapply(
    float* __restrict__ h, const float* __restrict__ mu, const float* __restrict__ rstd,
    const float* __restrict__ gamma, const float* __restrict__ beta)
{
    const int e = blockIdx.x * 256 + threadIdx.x;
    const int jb = (e & 255) * 4;
    float4 v = ((float4*)h)[e];
    v.x = fmaxf((v.x - mu[jb+0]) * rstd[jb+0] * gamma[jb+0] + beta[jb+0], 0.f);
    v.y = fmaxf((v.y - mu[jb+1]) * rstd[jb+1] * gamma[jb+1] + beta[jb+1], 0.f);
    v.z = fmaxf((v.z - mu[jb+2]) * rstd[jb+2] * gamma[jb+2] + beta[jb+2], 0.f);
    v.w = fmaxf((v.w - mu[jb+3]) * rstd[jb+3] * gamma[jb+3] + beta[jb+3], 0.f);
    ((float4*)h)[e] = v;
}

__global__ __launch_bounds__(256) void k_gemm2(
    const float* __restrict__ h, const float* __restrict__ W2,
    const float* __restrict__ b2, float* __restrict__ out0)
{
    __shared__ __align__(16) float hs[8 * 1024];
    const int i0 = blockIdx.x * 8;
    const int j = threadIdx.x;

    const float4* hg = (const float4*)(h + (size_t)i0 * 1024);
    float4* hl = (float4*)hs;
    #pragma unroll
    for (int e = 0; e < 8; ++e) hl[e * 256 + j] = hg[e * 256 + j];
    __syncthreads();

    float acc[8];
    #pragma unroll
    for (int r = 0; r < 8; ++r) acc[r] = 0.f;
    const float4* wr = (const float4*)(W2 + (size_t)j * 1024);
    const float4* hf = (const float4*)hs;
    #pragma unroll 4
    for (int k4 = 0; k4 < 256; ++k4) {
        const float4 w = wr[k4];
        #pragma unroll
        for (int r = 0; r < 8; ++r) {
            const float4 a = hf[r * 256 + k4];
            acc[r] += a.x*w.x + a.y*w.y + a.z*w.z + a.w*w.w;
        }
    }
    const float bb = b2[j];
    #pragma unroll
    for (int r = 0; r < 8; ++r)
        out0[(size_t)(i0 + r) * 256 + j] = acc[r] + bb;
}

// ---------------------------------------------------------------------------
extern "C" void kernel_launch(void* const* d_in, const int* in_sizes, int n_in,
                              void* d_out, int out_size, void* d_ws, size_t ws_size,
                              hipStream_t stream) {
    const float* feat0 = (const float*)d_in[0];
    const float* feat1 = (const float*)d_in[1];
    const float* W1    = (const float*)d_in[2];
    const float* b1    = (const float*)d_in[3];
    const float* gamma = (const float*)d_in[4];
    const float* beta  = (const float*)d_in[5];
    const float* W2    = (const float*)d_in[6];
    const float* b2    = (const float*)d_in[7];
    const float* W3    = (const float*)d_in[8];
    const float* b3    = (const float*)d_in[9];
    const float* W4    = (const float*)d_in[10];
    const float* b4    = (const float*)d_in[11];
    const int* patch_id0 = (const int*)d_in[12];
    const int* patch_id1 = (const int*)d_in[13];
    const int* local_id0 = (const int*)d_in[14];
    const int* local_id1 = (const int*)d_in[15];

    float* out0 = (float*)d_out;                 // (512, 256)
    float* out1 = out0 + 512 * 256;              // (4096, 41, 256)

    // workspace layout (floats)
    float* ws    = (float*)d_ws;
    float* x0m   = ws;                    // 262144
    float* h     = ws + 262144;           // 524288
    float* mu    = ws + 786432;           // 1024
    float* rstd  = ws + 787456;           // 1024
    int*   idx   = (int*)(ws + 788480);   // 4096*41 ints (167936 slots)
    float* W3T   = ws + 956416;           // 16384
    float* W4T   = ws + 972800;           // 65536
    float* ybuf  = ws + 1038336;          // 16 MB (loop) or 128 MB (all-img)

    const int YB_STRIDE = 16384 * 256;    // floats per image in ybuf

    const size_t NEED_C = (size_t)(1038336 + 4194304) * 4;              // ~20.9 MB
    const size_t NEED_B = (size_t)(1038336 + 4194304 + 8388608) * 4;    // ~54.5 MB
    const size_t NEED_A = (size_t)(1038336 + 33554432 + 8388608) * 4;   // ~172 MB

    if (ws_size >= NEED_C) {
        k_wtrans<<<256, 256, 0, stream>>>(W3, W4, W3T, W4T);

        if (ws_size >= NEED_A) {
            // all-images path: single launches, dedup across full batch
            float* featT = ws + 1038336 + 33554432;
            k_transpose1<<<dim3(256, 8), 256, 0, stream>>>(feat1, featT);
            k_sims1T<<<4096, 128, 0, stream>>>(featT, patch_id1, local_id1, idx);
            k_mlp_pix2<<<4096, 256, 0, stream>>>(feat1, W3T, b3, W4T, b4,
                                                 ybuf, YB_STRIDE);
            k_gather1<<<4096, 256, 0, stream>>>(ybuf, YB_STRIDE, idx, out1);
        } else {
            if (ws_size >= NEED_B) {
                float* featT = ws + 1038336 + 4194304;
                k_transpose1<<<dim3(256, 8), 256, 0, stream>>>(feat1, featT);
                k_sims1T<<<4096, 128, 0, stream>>>(featT, patch_id1, local_id1, idx);
            } else {
                k_sims1<<<4096, 128, 0, stream>>>(feat1, patch_id1, local_id1, idx);
            }
            for (int b = 0; b < 8; ++b) {
                k_mlp_pix2<<<512, 256, 0, stream>>>(
                    feat1 + (size_t)b * 64 * 16384, W3T, b3, W4T, b4, ybuf, 0);
                k_gather1<<<512, 256, 0, stream>>>(
                    ybuf, 0, idx + (size_t)b * 512 * 41,
                    out1 + (size_t)b * 512 * 41 * 256);
            }
        }
    } else {
        k_branch1<<<4096, 256, 0, stream>>>(feat1, patch_id1, local_id1,
                                            W3, b3, W4, b4, out1);
    }

    // branch 0 chain
    k_sample0<<<512, 64, 0, stream>>>(feat0, patch_id0, local_id0, x0m);
    k_gemm1<<<dim3(2, 64), 128, 0, stream>>>(x0m, W1, b1, h);
    k_bnstats<<<1024, 64, 0, stream>>>(h, mu, rstd);
    k_bnapply<<<512, 256, 0, stream>>>(h, mu, rstd, gamma, beta);
    k_gemm2<<<64, 256, 0, stream>>>(h, W2, b2, out0);
}

// Round 4
// 612.042 us; speedup vs baseline: 2.0428x; 1.3009x over previous
//
#include <hip/hip_runtime.h>
#include <math.h>

typedef _Float16 f16x8 __attribute__((ext_vector_type(8)));
typedef float f32x4 __attribute__((ext_vector_type(4)));

// ===========================================================================
// Branch-1 pipeline (tier A, large ws):
//   P) k_wprep:      pack W3/W4 into f16 hi/lo B-fragment order (one-time).
//   T) k_transpose1: feat1 (C,HW) -> featT (HW,C) per image.
//   A) k_sims1T:     per (b,n) fp64 cosine sims + stable top-40 -> pixel ids.
//   B) k_mlp_mfma:   dense MLP for ALL pixels on MFMA (f16 hi/lo split,
//                    3 MFMAs per product; fp32 accumulate) + L2-norm.
//   C) k_gather1:    out1[bn, mi, :] = ybuf[img, pix, :]
// Tiers B/C/fallback: verified fp32 paths from earlier rounds.
// ===========================================================================

// Pack B-fragments: PB[n-tile][k-step][lane][j] = (f16) W[n][k],
// n = nt*16 + (lane&15), k = ks*32 + (lane>>4)*8 + j.  hi/lo split.
__global__ __launch_bounds__(256) void k_wprep(
    const float* __restrict__ W3, const float* __restrict__ W4,
    unsigned short* __restrict__ PB3h, unsigned short* __restrict__ PB3l,
    unsigned short* __restrict__ PB4h, unsigned short* __restrict__ PB4l)
{
    const int e = blockIdx.x * 256 + threadIdx.x;    // 0..65535
    if (e < 16384) {  // W3: 16 nt x 2 ks x 64 lanes x 8
        const int j = e & 7, l = (e >> 3) & 63, ks = (e >> 9) & 1, nt = e >> 10;
        const int n = nt * 16 + (l & 15);
        const int k = ks * 32 + (l >> 4) * 8 + j;
        const float w = W3[n * 64 + k];
        const _Float16 hi = (_Float16)w;
        const _Float16 lo = (_Float16)(w - (float)hi);
        ((_Float16*)PB3h)[e] = hi;
        ((_Float16*)PB3l)[e] = lo;
    }
    {  // W4: 16 nt x 8 ks x 64 lanes x 8
        const int j = e & 7, l = (e >> 3) & 63, ks = (e >> 9) & 7, nt = e >> 12;
        const int n = nt * 16 + (l & 15);
        const int k = ks * 32 + (l >> 4) * 8 + j;
        const float w = W4[n * 256 + k];
        const _Float16 hi = (_Float16)w;
        const _Float16 lo = (_Float16)(w - (float)hi);
        ((_Float16*)PB4h)[e] = hi;
        ((_Float16*)PB4l)[e] = lo;
    }
}

__global__ __launch_bounds__(256) void k_transpose1(
    const float* __restrict__ feat1, float* __restrict__ featT)
{
    __shared__ float tile[64][65];
    const int b = blockIdx.y;
    const int p0 = blockIdx.x * 64;
    const int tid = threadIdx.x;
    const float* fb = feat1 + (size_t)b * 64 * 16384;
    float* ft = featT + (size_t)b * 16384 * 64;
    #pragma unroll
    for (int it = 0; it < 16; ++it) {
        const int e = it * 256 + tid;
        const int c = e >> 6, p = e & 63;
        tile[p][c] = fb[(size_t)c * 16384 + p0 + p];
    }
    __syncthreads();
    #pragma unroll
    for (int it = 0; it < 16; ++it) {
        const int e = it * 256 + tid;
        const int p = e >> 6, c = e & 63;
        ft[(size_t)(p0 + p) * 64 + c] = tile[p][c];
    }
}

__global__ __launch_bounds__(128) void k_sims1T(
    const float* __restrict__ featT, const int* __restrict__ patch_id1,
    const int* __restrict__ local_id1, int* __restrict__ idx)
{
    __shared__ float cen[64];
    __shared__ double sims[80];
    __shared__ double cnorm;

    const int row = blockIdx.x;          // 0..4095
    const int b = row >> 9;
    const int n = row & 511;
    const int tid = threadIdx.x;
    const float* ft = featT + (size_t)b * 16384 * 64;
    const int pid = patch_id1[n];
    const int* lids = local_id1 + n * 80;

    if (tid < 64) cen[tid] = ft[(size_t)pid * 64 + tid];
    __syncthreads();

    if (tid < 64) {
        double v = (double)cen[tid];
        double s = v * v;
        for (int o = 32; o > 0; o >>= 1) s += __shfl_down(s, o);
        if (tid == 0) { s = sqrt(s); cnorm = (s < 1e-12) ? 1e-12 : s; }
    }
    __syncthreads();

    if (tid < 80) {
        const float4* rp = (const float4*)(ft + (size_t)lids[tid] * 64);
        double d = 0.0, q = 0.0;
        #pragma unroll
        for (int k = 0; k < 16; ++k) {
            const float4 v4 = rp[k];
            double v;
            v = (double)v4.x; d += v * (double)cen[4*k+0]; q += v*v;
            v = (double)v4.y; d += v * (double)cen[4*k+1]; q += v*v;
            v = (double)v4.z; d += v * (double)cen[4*k+2]; q += v*v;
            v = (double)v4.w; d += v * (double)cen[4*k+3]; q += v*v;
        }
        double nl = sqrt(q); if (nl < 1e-12) nl = 1e-12;
        sims[tid] = d / (nl * cnorm);
    }
    __syncthreads();

    if (tid < 80) {
        const double s = sims[tid];
        int rank = 0;
        for (int j = 0; j < 80; ++j) {
            const double sj = sims[j];
            rank += (sj > s) || (sj == s && j < tid);
        }
        if (rank < 40) idx[row * 41 + 1 + rank] = lids[tid];
    }
    if (tid == 0) idx[row * 41] = pid;
}

__global__ __launch_bounds__(128) void k_sims1(
    const float* __restrict__ feat1, const int* __restrict__ patch_id1,
    const int* __restrict__ local_id1, int* __restrict__ idx)
{
    __shared__ float cen[64];
    __shared__ double sims[80];
    __shared__ double cnorm;

    const int row = blockIdx.x;
    const int b = row >> 9;
    const int n = row & 511;
    const int tid = threadIdx.x;
    const float* fb = feat1 + (size_t)b * 64 * 16384;
    const int pid = patch_id1[n];
    const int* lids = local_id1 + n * 80;

    if (tid < 64) cen[tid] = fb[(size_t)tid * 16384 + pid];
    __syncthreads();

    if (tid < 64) {
        double v = (double)cen[tid];
        double s = v * v;
        for (int o = 32; o > 0; o >>= 1) s += __shfl_down(s, o);
        if (tid == 0) { s = sqrt(s); cnorm = (s < 1e-12) ? 1e-12 : s; }
    }
    __syncthreads();

    if (tid < 80) {
        const int lpix = lids[tid];
        double d = 0.0, q = 0.0;
        for (int c = 0; c < 64; ++c) {
            double v = (double)fb[(size_t)c * 16384 + lpix];
            d += v * (double)cen[c];
            q += v * v;
        }
        double nl = sqrt(q); if (nl < 1e-12) nl = 1e-12;
        sims[tid] = d / (nl * cnorm);
    }
    __syncthreads();

    if (tid < 80) {
        const double s = sims[tid];
        int rank = 0;
        for (int j = 0; j < 80; ++j) {
            const double sj = sims[j];
            rank += (sj > s) || (sj == s && j < tid);
        }
        if (rank < 40) idx[row * 41 + 1 + rank] = lids[tid];
    }
    if (tid == 0) idx[row * 41] = pid;
}

// ---------------------------------------------------------------------------
// MFMA MLP: 32 pixels/block, 256 thr = 4 waves.
// wave w: m-tile mt = w&1 (16 rows), n-half nh = w>>1 (8 of 16 n-tiles).
// f16 hi/lo split: x*w ~= lo*hi + hi*lo + hi*hi, fp32 accumulate in MFMA.
// C/D layout (verified m89): col = lane&15, row = (lane>>4)*4 + reg.
// A: row = lane&15, k = (lane>>4)*8 + j.   B: col = lane&15, same k.
// ---------------------------------------------------------------------------
__global__ __launch_bounds__(256) void k_mlp_mfma(
    const float* __restrict__ featb,
    const unsigned short* __restrict__ PB3h, const unsigned short* __restrict__ PB3l,
    const unsigned short* __restrict__ PB4h, const unsigned short* __restrict__ PB4l,
    const float* __restrict__ b3, const float* __restrict__ b4,
    float* __restrict__ ybuf)
{
    __shared__ _Float16 XH[32][72];      // stride 72 f16 = 36 dwords -> bank-balanced
    __shared__ _Float16 XL[32][72];
    __shared__ float T1[32][260];        // stride 260 dwords -> bank-balanced
    __shared__ float rsums[2][2][16];

    const int tid = threadIdx.x;
    const int blk = blockIdx.x;
    const int img = blk >> 9;
    const int p0 = (blk & 511) * 32;
    const float* fb = featb + (size_t)img * 64 * 16384;
    float* yb = ybuf + (size_t)img * (size_t)(16384 * 256);

    // X fill (coalesced) + f16 hi/lo split
    {
        const int p = tid & 31;
        const int cg = tid >> 5;
        #pragma unroll
        for (int k = 0; k < 8; ++k) {
            const int c = cg * 8 + k;
            const float v = fb[(size_t)c * 16384 + p0 + p];
            const _Float16 hi = (_Float16)v;
            XH[p][c] = hi;
            XL[p][c] = (_Float16)(v - (float)hi);
        }
    }
    __syncthreads();

    const int lane = tid & 63;
    const int w = tid >> 6;
    const int mt = w & 1;
    const int nh = w >> 1;
    const int lrow = lane & 15;
    const int kblk = lane >> 4;

    // ---- stage 1: T1 = relu(X @ W3^T + b3) ----
    {
        f16x8 ah[2], al[2];
        #pragma unroll
        for (int ks = 0; ks < 2; ++ks) {
            ah[ks] = *(const f16x8*)&XH[mt*16 + lrow][ks*32 + kblk*8];
            al[ks] = *(const f16x8*)&XL[mt*16 + lrow][ks*32 + kblk*8];
        }
        const f16x8* B3H = (const f16x8*)PB3h;
        const f16x8* B3L = (const f16x8*)PB3l;
        #pragma unroll
        for (int t = 0; t < 8; ++t) {
            const int nt = nh*8 + t;
            f32x4 acc = {0.f, 0.f, 0.f, 0.f};
            #pragma unroll
            for (int ks = 0; ks < 2; ++ks) {
                const f16x8 bh = B3H[(nt*2 + ks)*64 + lane];
                const f16x8 bl = B3L[(nt*2 + ks)*64 + lane];
                acc = __builtin_amdgcn_mfma_f32_16x16x32_f16(al[ks], bh, acc, 0, 0, 0);
                acc = __builtin_amdgcn_mfma_f32_16x16x32_f16(ah[ks], bl, acc, 0, 0, 0);
                acc = __builtin_amdgcn_mfma_f32_16x16x32_f16(ah[ks], bh, acc, 0, 0, 0);
            }
            const float bias = b3[nt*16 + lrow];
            #pragma unroll
            for (int r = 0; r < 4; ++r)
                T1[mt*16 + kblk*4 + r][nt*16 + lrow] = fmaxf(acc[r] + bias, 0.f);
        }
    }
    __syncthreads();

    // ---- stage 2: Y = T1 @ W4^T + b4, L2-normalize, store ----
    f32x4 acc2[8];
    #pragma unroll
    for (int t = 0; t < 8; ++t) acc2[t] = (f32x4){0.f, 0.f, 0.f, 0.f};
    {
        const f16x8* B4H = (const f16x8*)PB4h;
        const f16x8* B4L = (const f16x8*)PB4l;
        #pragma unroll 2
        for (int ks = 0; ks < 8; ++ks) {
            float a[8];
            *(float4*)&a[0] = *(const float4*)&T1[mt*16 + lrow][ks*32 + kblk*8];
            *(float4*)&a[4] = *(const float4*)&T1[mt*16 + lrow][ks*32 + kblk*8 + 4];
            f16x8 ah2, al2;
            #pragma unroll
            for (int j = 0; j < 8; ++j) {
                const _Float16 hi = (_Float16)a[j];
                ah2[j] = hi;
                al2[j] = (_Float16)(a[j] - (float)hi);
            }
            #pragma unroll
            for (int t = 0; t < 8; ++t) {
                const int nt = nh*8 + t;
                const f16x8 bh = B4H[(nt*8 + ks)*64 + lane];
                const f16x8 bl = B4L[(nt*8 + ks)*64 + lane];
                acc2[t] = __builtin_amdgcn_mfma_f32_16x16x32_f16(al2, bh, acc2[t], 0, 0, 0);
                acc2[t] = __builtin_amdgcn_mfma_f32_16x16x32_f16(ah2, bl, acc2[t], 0, 0, 0);
                acc2[t] = __builtin_amdgcn_mfma_f32_16x16x32_f16(ah2, bh, acc2[t], 0, 0, 0);
            }
        }
    }
    // bias + row sum of squares
    float p[4] = {0.f, 0.f, 0.f, 0.f};
    #pragma unroll
    for (int t = 0; t < 8; ++t) {
        const float bias = b4[(nh*8 + t)*16 + lrow];
        #pragma unroll
        for (int r = 0; r < 4; ++r) {
            acc2[t][r] += bias;
            p[r] += acc2[t][r] * acc2[t][r];
        }
    }
    #pragma unroll
    for (int r = 0; r < 4; ++r)
        for (int o = 1; o < 16; o <<= 1) p[r] += __shfl_xor(p[r], o);
    if (lrow == 0) {
        #pragma unroll
        for (int r = 0; r < 4; ++r) rsums[mt][nh][kblk*4 + r] = p[r];
    }
    __syncthreads();
    float inv[4];
    #pragma unroll
    for (int r = 0; r < 4; ++r) {
        const float s = rsums[mt][0][kblk*4 + r] + rsums[mt][1][kblk*4 + r];
        inv[r] = 1.f / (sqrtf(s) + 1e-7f);
    }
    #pragma unroll
    for (int t = 0; t < 8; ++t) {
        const int col = (nh*8 + t)*16 + lrow;
        #pragma unroll
        for (int r = 0; r < 4; ++r)
            yb[(size_t)(p0 + mt*16 + kblk*4 + r) * 256 + col] = acc2[t][r] * inv[r];
    }
}

// fp32 MLP (verified) — tiers B/C.
__global__ __launch_bounds__(256) void k_mlp_pix2(
    const float* __restrict__ featb,
    const float* __restrict__ W3T, const float* __restrict__ b3,
    const float* __restrict__ W4T, const float* __restrict__ b4,
    float* __restrict__ ybuf, int ybufStride)
{
    __shared__ __align__(16) float xs[32 * 68];
    __shared__ __align__(16) float t1s[32 * 256];

    const int tid = threadIdx.x;
    const int blk = blockIdx.x;
    const int img = blk >> 9;
    const int p0 = (blk & 511) * 32;
    const float* fb = featb + (size_t)img * 64 * 16384;
    float* yb = ybuf + (size_t)img * (size_t)ybufStride;

    {
        const int p = tid & 31;
        const int cg = tid >> 5;
        #pragma unroll
        for (int k = 0; k < 8; ++k) {
            const int c = cg * 8 + k;
            xs[p * 68 + c] = fb[(size_t)c * 16384 + p0 + p];
        }
    }
    __syncthreads();

    const int jg = tid & 63;
    const int g = tid >> 6;
    const int j0 = jg * 4;
    const int mb = g * 8;

    {
        float acc[8][4];
        #pragma unroll
        for (int r = 0; r < 8; ++r) {
            acc[r][0] = 0.f; acc[r][1] = 0.f; acc[r][2] = 0.f; acc[r][3] = 0.f;
        }
        const float4* Wf = (const float4*)W3T;
        const float4* xsf = (const float4*)xs;
        #pragma unroll 4
        for (int cq = 0; cq < 16; ++cq) {
            const float4 wA = Wf[(cq * 4 + 0) * 64 + jg];
            const float4 wB = Wf[(cq * 4 + 1) * 64 + jg];
            const float4 wC = Wf[(cq * 4 + 2) * 64 + jg];
            const float4 wD = Wf[(cq * 4 + 3) * 64 + jg];
            #pragma unroll
            for (int r = 0; r < 8; ++r) {
                const float4 x4 = xsf[(mb + r) * 17 + cq];
                acc[r][0] += x4.x*wA.x + x4.y*wB.x + x4.z*wC.x + x4.w*wD.x;
                acc[r][1] += x4.x*wA.y + x4.y*wB.y + x4.z*wC.y + x4.w*wD.y;
                acc[r][2] += x4.x*wA.z + x4.y*wB.z + x4.z*wC.z + x4.w*wD.z;
                acc[r][3] += x4.x*wA.w + x4.y*wB.w + x4.z*wC.w + x4.w*wD.w;
            }
        }
        const float bb0 = b3[j0], bb1 = b3[j0+1], bb2 = b3[j0+2], bb3 = b3[j0+3];
        #pragma unroll
        for (int r = 0; r < 8; ++r) {
            float4 o4;
            o4.x = fmaxf(acc[r][0] + bb0, 0.f);
            o4.y = fmaxf(acc[r][1] + bb1, 0.f);
            o4.z = fmaxf(acc[r][2] + bb2, 0.f);
            o4.w = fmaxf(acc[r][3] + bb3, 0.f);
            *(float4*)&t1s[(mb + r) * 256 + j0] = o4;
        }
    }
    __syncthreads();

    {
        float acc[8][4];
        #pragma unroll
        for (int r = 0; r < 8; ++r) {
            acc[r][0] = 0.f; acc[r][1] = 0.f; acc[r][2] = 0.f; acc[r][3] = 0.f;
        }
        const float4* Wf = (const float4*)W4T;
        const float4* t1f = (const float4*)t1s;
        #pragma unroll 2
        for (int kq = 0; kq < 64; ++kq) {
            const float4 wA = Wf[(kq * 4 + 0) * 64 + jg];
            const float4 wB = Wf[(kq * 4 + 1) * 64 + jg];
            const float4 wC = Wf[(kq * 4 + 2) * 64 + jg];
            const float4 wD = Wf[(kq * 4 + 3) * 64 + jg];
            #pragma unroll
            for (int r = 0; r < 8; ++r) {
                const float4 t4 = t1f[(mb + r) * 64 + kq];
                acc[r][0] += t4.x*wA.x + t4.y*wB.x + t4.z*wC.x + t4.w*wD.x;
                acc[r][1] += t4.x*wA.y + t4.y*wB.y + t4.z*wC.y + t4.w*wD.y;
                acc[r][2] += t4.x*wA.z + t4.y*wB.z + t4.z*wC.z + t4.w*wD.z;
                acc[r][3] += t4.x*wA.w + t4.y*wB.w + t4.z*wC.w + t4.w*wD.w;
            }
        }
        const float bb0 = b4[j0], bb1 = b4[j0+1], bb2 = b4[j0+2], bb3 = b4[j0+3];
        #pragma unroll
        for (int r = 0; r < 8; ++r) {
            const float y0 = acc[r][0] + bb0;
            const float y1 = acc[r][1] + bb1;
            const float y2 = acc[r][2] + bb2;
            const float y3 = acc[r][3] + bb3;
            float p = y0*y0 + y1*y1 + y2*y2 + y3*y3;
            for (int o = 1; o < 64; o <<= 1) p += __shfl_xor(p, o);
            const float inv = 1.f / (sqrtf(p) + 1e-7f);
            float4 o4 = make_float4(y0*inv, y1*inv, y2*inv, y3*inv);
            *(float4*)&yb[(size_t)(p0 + mb + r) * 256 + j0] = o4;
        }
    }
}

__global__ __launch_bounds__(256) void k_wtrans(
    const float* __restrict__ W3, const float* __restrict__ W4,
    float* __restrict__ W3T, float* __restrict__ W4T)
{
    const int t = threadIdx.x;
    const int j = blockIdx.x;
    W4T[(size_t)t * 256 + j] = W4[(size_t)j * 256 + t];
    if (j < 64) W3T[(size_t)j * 256 + t] = W3[(size_t)t * 64 + j];
}

__global__ __launch_bounds__(256) void k_gather1(
    const float* __restrict__ ybuf, int ybufStride,
    const int* __restrict__ idxb, float* __restrict__ out1b)
{
    __shared__ int pix[41];
    const int bn = blockIdx.x;
    const int img = bn >> 9;
    const int tid = threadIdx.x;
    if (tid < 41) pix[tid] = idxb[bn * 41 + tid];
    __syncthreads();
    const float4* yb4 = (const float4*)(ybuf + (size_t)img * (size_t)ybufStride);
    float4* o4 = (float4*)(out1b + (size_t)bn * 41 * 256);
    for (int e = tid; e < 41 * 64; e += 256) {
        const int mi = e >> 6, j4 = e & 63;
        o4[mi * 64 + j4] = yb4[pix[mi] * 64 + j4];
    }
}

// ===========================================================================
// FALLBACK: original fused branch-1 kernel (verified)
// ===========================================================================
__global__ __launch_bounds__(256) void k_branch1(
    const float* __restrict__ feat1, const int* __restrict__ patch_id1,
    const int* __restrict__ local_id1, const float* __restrict__ W3,
    const float* __restrict__ b3, const float* __restrict__ W4,
    const float* __restrict__ b4, float* __restrict__ out1)
{
    __shared__ __align__(16) float xs[44 * 64];
    __shared__ __align__(16) float t1s[44 * 256];
    __shared__ double sims[80];
    __shared__ int winners[40];
    __shared__ float cen[64];
    __shared__ double cnorm;

    const int row = blockIdx.x;
    const int b = row >> 9;
    const int n = row & 511;
    const int tid = threadIdx.x;
    const float* fb = feat1 + (size_t)b * 64 * 16384;
    const int pid = patch_id1[n];
    const int* lids = local_id1 + n * 80;

    if (tid < 64) cen[tid] = fb[(size_t)tid * 16384 + pid];
    __syncthreads();

    if (tid < 64) {
        double v = (double)cen[tid];
        double s = v * v;
        for (int o = 32; o > 0; o >>= 1) s += __shfl_down(s, o);
        if (tid == 0) { s = sqrt(s); cnorm = (s < 1e-12) ? 1e-12 : s; }
    }
    __syncthreads();

    if (tid < 80) {
        const int lpix = lids[tid];
        double d = 0.0, q = 0.0;
        for (int c = 0; c < 64; ++c) {
            double v = (double)fb[(size_t)c * 16384 + lpix];
            d += v * (double)cen[c];
            q += v * v;
        }
        double nl = sqrt(q); if (nl < 1e-12) nl = 1e-12;
        sims[tid] = d / (nl * cnorm);
    }
    __syncthreads();

    if (tid < 80) {
        const double s = sims[tid];
        int rank = 0;
        for (int j = 0; j < 80; ++j) {
            const double sj = sims[j];
            rank += (sj > s) || (sj == s && j < tid);
        }
        if (rank < 40) winners[rank] = tid;
    }
    __syncthreads();

    for (int m = tid; m < 44 * 64; m += 256) {
        const int mi = m >> 6, c = m & 63;
        float v;
        if (mi >= 1 && mi <= 40) v = fb[(size_t)c * 16384 + lids[winners[mi - 1]]];
        else v = cen[c];
        xs[m] = v;
    }
    __syncthreads();

    const int jg = tid & 63;
    const int g = tid >> 6;
    const int j0 = jg * 4;
    const int mb = g * 11;

    {
        float acc[11][4];
        #pragma unroll
        for (int r = 0; r < 11; ++r) {
            acc[r][0] = 0.f; acc[r][1] = 0.f; acc[r][2] = 0.f; acc[r][3] = 0.f;
        }
        const float4* W3f = (const float4*)W3;
        const float4* xsf = (const float4*)xs;
        #pragma unroll 4
        for (int c4 = 0; c4 < 16; ++c4) {
            const float4 w0 = W3f[(j0 + 0) * 16 + c4];
            const float4 w1 = W3f[(j0 + 1) * 16 + c4];
            const float4 w2 = W3f[(j0 + 2) * 16 + c4];
            const float4 w3 = W3f[(j0 + 3) * 16 + c4];
            #pragma unroll
            for (int r = 0; r < 11; ++r) {
                const float4 x4 = xsf[(mb + r) * 16 + c4];
                acc[r][0] += x4.x*w0.x + x4.y*w0.y + x4.z*w0.z + x4.w*w0.w;
                acc[r][1] += x4.x*w1.x + x4.y*w1.y + x4.z*w1.z + x4.w*w1.w;
                acc[r][2] += x4.x*w2.x + x4.y*w2.y + x4.z*w2.z + x4.w*w2.w;
                acc[r][3] += x4.x*w3.x + x4.y*w3.y + x4.z*w3.z + x4.w*w3.w;
            }
        }
        const float bb0 = b3[j0], bb1 = b3[j0+1], bb2 = b3[j0+2], bb3 = b3[j0+3];
        #pragma unroll
        for (int r = 0; r < 11; ++r) {
            float4 o4;
            o4.x = fmaxf(acc[r][0] + bb0, 0.f);
            o4.y = fmaxf(acc[r][1] + bb1, 0.f);
            o4.z = fmaxf(acc[r][2] + bb2, 0.f);
            o4.w = fmaxf(acc[r][3] + bb3, 0.f);
            *(float4*)&t1s[(mb + r) * 256 + j0] = o4;
        }
    }
    __syncthreads();

    {
        float acc[11][4];
        #pragma unroll
        for (int r = 0; r < 11; ++r) {
            acc[r][0] = 0.f; acc[r][1] = 0.f; acc[r][2] = 0.f; acc[r][3] = 0.f;
        }
        const float4* W4f = (const float4*)W4;
        const float4* t1f = (const float4*)t1s;
        #pragma unroll 2
        for (int j4 = 0; j4 < 64; ++j4) {
            const float4 w0 = W4f[(j0 + 0) * 64 + j4];
            const float4 w1 = W4f[(j0 + 1) * 64 + j4];
            const float4 w2 = W4f[(j0 + 2) * 64 + j4];
            const float4 w3 = W4f[(j0 + 3) * 64 + j4];
            #pragma unroll
            for (int r = 0; r < 11; ++r) {
                const float4 t4 = t1f[(mb + r) * 64 + j4];
                acc[r][0] += t4.x*w0.x + t4.y*w0.y + t4.z*w0.z + t4.w*w0.w;
                acc[r][1] += t4.x*w1.x + t4.y*w1.y + t4.z*w1.z + t4.w*w1.w;
                acc[r][2] += t4.x*w2.x + t4.y*w2.y + t4.z*w2.z + t4.w*w2.w;
                acc[r][3] += t4.x*w3.x + t4.y*w3.y + t4.z*w3.z + t4.w*w3.w;
            }
        }
        const float bb0 = b4[j0], bb1 = b4[j0+1], bb2 = b4[j0+2], bb3 = b4[j0+3];
        #pragma unroll
        for (int r = 0; r < 11; ++r) {
            const float y0 = acc[r][0] + bb0;
            const float y1 = acc[r][1] + bb1;
            const float y2 = acc[r][2] + bb2;
            const float y3 = acc[r][3] + bb3;
            float p = y0*y0 + y1*y1 + y2*y2 + y3*y3;
            for (int o = 1; o < 64; o <<= 1) p += __shfl_xor(p, o);
            const float inv = 1.f / (sqrtf(p) + 1e-7f);
            const int mi = mb + r;
            if (mi < 41) {
                float4 o4 = make_float4(y0*inv, y1*inv, y2*inv, y3*inv);
                *(float4*)&out1[((size_t)row * 41 + mi) * 256 + j0] = o4;
            }
        }
    }
}

// ---------------------------------------------------------------------------
// Branch 0 kernels
// ---------------------------------------------------------------------------
__global__ __launch_bounds__(64) void k_sample0(
    const float* __restrict__ feat0, const int* __restrict__ patch_id0,
    const int* __restrict__ local_id0, float* __restrict__ x0m)
{
    __shared__ float cen[512];
    __shared__ float loc[8][512];
    __shared__ double sims[8];
    __shared__ int winners[4];
    __shared__ double cnorm;

    const int row = blockIdx.x;
    const int b = row >> 6;
    const int n = row & 63;
    const int t = threadIdx.x;
    const float* fb = feat0 + (size_t)b * 512 * 64;
    const int pid = patch_id0[n];

    for (int c = t; c < 512; c += 64) cen[c] = fb[(size_t)c * 64 + pid];
    for (int l = 0; l < 8; ++l) {
        const int lp = local_id0[n * 8 + l];
        for (int c = t; c < 512; c += 64) loc[l][c] = fb[(size_t)c * 64 + lp];
    }
    __syncthreads();

    double cs = 0.0;
    for (int c = t; c < 512; c += 64) { double v = (double)cen[c]; cs += v * v; }
    for (int o = 32; o > 0; o >>= 1) cs += __shfl_down(cs, o);
    if (t == 0) { cs = sqrt(cs); cnorm = (cs < 1e-12) ? 1e-12 : cs; }
    __syncthreads();

    for (int l = 0; l < 8; ++l) {
        double d = 0.0, q = 0.0;
        for (int c = t; c < 512; c += 64) {
            double v = (double)loc[l][c];
            d += v * (double)cen[c];
            q += v * v;
        }
        for (int o = 32; o > 0; o >>= 1) { d += __shfl_down(d, o); q += __shfl_down(q, o); }
        if (t == 0) {
            double nl = sqrt(q); if (nl < 1e-12) nl = 1e-12;
            sims[l] = d / (nl * cnorm);
        }
    }
    __syncthreads();

    if (t < 8) {
        const double s = sims[t];
        int rank = 0;
        for (int j = 0; j < 8; ++j) {
            const double sj = sims[j];
            rank += (sj > s) || (sj == s && j < t);
        }
        if (rank < 4) winners[rank] = t;
    }
    __syncthreads();

    for (int c = t; c < 512; c += 64) {
        float a = cen[c];
        for (int r = 0; r < 4; ++r) a += loc[winners[r]][c];
        x0m[(size_t)row * 512 + c] = a * 0.2f;
    }
}

__global__ __launch_bounds__(128) void k_gemm1(
    const float* __restrict__ x, const float* __restrict__ W1,
    const float* __restrict__ b1, float* __restrict__ h)
{
    __shared__ __align__(16) float xsr[8 * 512];
    const int i0 = blockIdx.y * 8;
    const int tid = threadIdx.x;
    const int j0 = blockIdx.x * 512 + tid * 4;

    const float4* xg = (const float4*)(x + (size_t)i0 * 512);
    float4* xl = (float4*)xsr;
    #pragma unroll
    for (int e = 0; e < 8; ++e) xl[e * 128 + tid] = xg[e * 128 + tid];
    __syncthreads();

    float acc[8][4];
    #pragma unroll
    for (int r = 0; r < 8; ++r) {
        acc[r][0] = 0.f; acc[r][1] = 0.f; acc[r][2] = 0.f; acc[r][3] = 0.f;
    }
    const float4* W1f = (const float4*)W1;
    const float4* xf  = (const float4*)xsr;
    #pragma unroll 4
    for (int c4 = 0; c4 < 128; ++c4) {
        const float4 w0 = W1f[(size_t)(j0 + 0) * 128 + c4];
        const float4 w1 = W1f[(size_t)(j0 + 1) * 128 + c4];
        const float4 w2 = W1f[(size_t)(j0 + 2) * 128 + c4];
        const float4 w3 = W1f[(size_t)(j0 + 3) * 128 + c4];
        #pragma unroll
        for (int r = 0; r < 8; ++r) {
            const float4 x4 = xf[r * 128 + c4];
            acc[r][0] += x4.x*w0.x + x4.y*w0.y + x4.z*w0.z + x4.w*w0.w;
            acc[r][1] += x4.x*w1.x + x4.y*w1.y + x4.z*w1.z + x4.w*w1.w;
            acc[r][2] += x4.x*w2.x + x4.y*w2.y + x4.z*w2.z + x4.w*w2.w;
            acc[r][3] += x4.x*w3.x + x4.y*w3.y + x4.z*w3.z + x4.w*w3.w;
        }
    }
    const float bb0 = b1[j0], bb1 = b1[j0+1], bb2 = b1[j0+2], bb3 = b1[j0+3];
    #pragma unroll
    for (int r = 0; r < 8; ++r) {
        float4 o4 = make_float4(acc[r][0] + bb0, acc[r][1] + bb1,
                                acc[r][2] + bb2, acc[r][3] + bb3);
        *(float4*)&h[(size_t)(i0 + r) * 1024 + j0] = o4;
    }
}

__global__ __launch_bounds__(64) void k_bnstats(
    const float* __restrict__ h, float* __restrict__ mu, float* __restrict__ rstd)
{
    const int j = blockIdx.x;
    const int t = threadIdx.x;
    float s = 0.f, ss = 0.f;
    for (int i = t; i < 512; i += 64) {
        const float v = h[(size_t)i * 1024 + j];
        s += v; ss += v * v;
    }
    for (int o = 32; o > 0; o >>= 1) { s += __shfl_down(s, o); ss += __shfl_down(ss, o); }
    if (t == 0) {
        const float m = s * (1.f / 512.f);
        const float var = ss * (1.f / 512.f) - m * m;
        mu[j] = m;
        rstd[j] = rsqrtf(var + 1e-5f);
    }
}

__global__ __launch_bounds__(256) void k_bnapply(
    float* __restrict__ h, const float* __restrict__ mu, const float* __restrict__ rstd,
    const float* __restrict__ gamma, const float* __restrict__ beta)
{
    const int e = blockIdx.x * 256 + threadIdx.x;
    const int jb = (e & 255) * 4;
    float4 v = ((float4*)h)[e];
    v.x = fmaxf((v.x - mu[jb+0]) * rstd[jb+0] * gamma[jb+0] + beta[jb+0], 0.f);
    v.y = fmaxf((v.y - mu[jb+1]) * rstd[jb+1] * gamma[jb+1] + beta[jb+1], 0.f);
    v.z = fmaxf((v.z - mu[jb+2]) * rstd[jb+2] * gamma[jb+2] + beta[jb+2], 0.f);
    v.w = fmaxf((v.w - mu[jb+3]) * rstd[jb+3] * gamma[jb+3] + beta[jb+3], 0.f);
    ((float4*)h)[e] = v;
}

__global__ __launch_bounds__(256) void k_gemm2(
    const float* __restrict__ h, const float* __restrict__ W2,
    const float* __restrict__ b2, float* __restrict__ out0)
{
    __shared__ __align__(16) float hs[8 * 1024];
    const int i0 = blockIdx.x * 8;
    const int j = threadIdx.x;

    const float4* hg = (const float4*)(h + (size_t)i0 * 1024);
    float4* hl = (float4*)hs;
    #pragma unroll
    for (int e = 0; e < 8; ++e) hl[e * 256 + j] = hg[e * 256 + j];
    __syncthreads();

    float acc[8];
    #pragma unroll
    for (int r = 0; r < 8; ++r) acc[r] = 0.f;
    const float4* wr = (const float4*)(W2 + (size_t)j * 1024);
    const float4* hf = (const float4*)hs;
    #pragma unroll 4
    for (int k4 = 0; k4 < 256; ++k4) {
        const float4 w = wr[k4];
        #pragma unroll
        for (int r = 0; r < 8; ++r) {
            const float4 a = hf[r * 256 + k4];
            acc[r] += a.x*w.x + a.y*w.y + a.z*w.z + a.w*w.w;
        }
    }
    const float bb = b2[j];
    #pragma unroll
    for (int r = 0; r < 8; ++r)
        out0[(size_t)(i0 + r) * 256 + j] = acc[r] + bb;
}

// ---------------------------------------------------------------------------
extern "C" void kernel_launch(void* const* d_in, const int* in_sizes, int n_in,
                              void* d_out, int out_size, void* d_ws, size_t ws_size,
                              hipStream_t stream) {
    const float* feat0 = (const float*)d_in[0];
    const float* feat1 = (const float*)d_in[1];
    const float* W1    = (const float*)d_in[2];
    const float* b1    = (const float*)d_in[3];
    const float* gamma = (const float*)d_in[4];
    const float* beta  = (const float*)d_in[5];
    const float* W2    = (const float*)d_in[6];
    const float* b2    = (const float*)d_in[7];
    const float* W3    = (const float*)d_in[8];
    const float* b3    = (const float*)d_in[9];
    const float* W4    = (const float*)d_in[10];
    const float* b4    = (const float*)d_in[11];
    const int* patch_id0 = (const int*)d_in[12];
    const int* patch_id1 = (const int*)d_in[13];
    const int* local_id0 = (const int*)d_in[14];
    const int* local_id1 = (const int*)d_in[15];

    float* out0 = (float*)d_out;                 // (512, 256)
    float* out1 = out0 + 512 * 256;              // (4096, 41, 256)

    // workspace layout (floats)
    float* ws    = (float*)d_ws;
    float* x0m   = ws;                    // 262144
    float* h     = ws + 262144;           // 524288
    float* mu    = ws + 786432;           // 1024
    float* rstd  = ws + 787456;           // 1024
    int*   idx   = (int*)(ws + 788480);   // 4096*41 ints (167936 slots)
    // region ws+956416 .. +1038336 (81920 floats): either W3T/W4T (fp32 path)
    // or the packed f16 hi/lo weight fragments (MFMA path).
    float* W3T   = ws + 956416;           // 16384
    float* W4T   = ws + 972800;           // 65536
    unsigned short* PB3h = (unsigned short*)(ws + 956416);   // 16384 u16
    unsigned short* PB3l = PB3h + 16384;
    unsigned short* PB4h = PB3l + 16384;                     // 65536 u16
    unsigned short* PB4l = PB4h + 65536;
    float* ybuf  = ws + 1038336;          // 16 MB (loop) or 128 MB (all-img)

    const int YB_STRIDE = 16384 * 256;    // floats per image in ybuf

    const size_t NEED_C = (size_t)(1038336 + 4194304) * 4;              // ~20.9 MB
    const size_t NEED_B = (size_t)(1038336 + 4194304 + 8388608) * 4;    // ~54.5 MB
    const size_t NEED_A = (size_t)(1038336 + 33554432 + 8388608) * 4;   // ~172 MB

    if (ws_size >= NEED_A) {
        // MFMA path: pack weights, full-batch single launches
        float* featT = ws + 1038336 + 33554432;
        k_wprep<<<256, 256, 0, stream>>>(W3, W4, PB3h, PB3l, PB4h, PB4l);
        k_transpose1<<<dim3(256, 8), 256, 0, stream>>>(feat1, featT);
        k_sims1T<<<4096, 128, 0, stream>>>(featT, patch_id1, local_id1, idx);
        k_mlp_mfma<<<4096, 256, 0, stream>>>(feat1, PB3h, PB3l, PB4h, PB4l,
                                             b3, b4, ybuf);
        k_gather1<<<4096, 256, 0, stream>>>(ybuf, YB_STRIDE, idx, out1);
    } else if (ws_size >= NEED_C) {
        k_wtrans<<<256, 256, 0, stream>>>(W3, W4, W3T, W4T);
        if (ws_size >= NEED_B) {
            float* featT = ws + 1038336 + 4194304;
            k_transpose1<<<dim3(256, 8), 256, 0, stream>>>(feat1, featT);
            k_sims1T<<<4096, 128, 0, stream>>>(featT, patch_id1, local_id1, idx);
        } else {
            k_sims1<<<4096, 128, 0, stream>>>(feat1, patch_id1, local_id1, idx);
        }
        for (int b = 0; b < 8; ++b) {
            k_mlp_pix2<<<512, 256, 0, stream>>>(
                feat1 + (size_t)b * 64 * 16384, W3T, b3, W4T, b4, ybuf, 0);
            k_gather1<<<512, 256, 0, stream>>>(
                ybuf, 0, idx + (size_t)b * 512 * 41,
                out1 + (size_t)b * 512 * 41 * 256);
        }
    } else {
        k_branch1<<<4096, 256, 0, stream>>>(feat1, patch_id1, local_id1,
                                            W3, b3, W4, b4, out1);
    }

    // branch 0 chain
    k_sample0<<<512, 64, 0, stream>>>(feat0, patch_id0, local_id0, x0m);
    k_gemm1<<<dim3(2, 64), 128, 0, stream>>>(x0m, W1, b1, h);
    k_bnstats<<<1024, 64, 0, stream>>>(h, mu, rstd);
    k_bnapply<<<512, 256, 0, stream>>>(h, mu, rstd, gamma, beta);
    k_gemm2<<<64, 256, 0, stream>>>(h, W2, b2, out0);
}

// Round 5
// 581.943 us; speedup vs baseline: 2.1484x; 1.0517x over previous
//
#include <hip/hip_runtime.h>
#include <math.h>

typedef _Float16 f16x8 __attribute__((ext_vector_type(8)));
typedef float f32x4 __attribute__((ext_vector_type(4)));

// ===========================================================================
// Branch-1 tier-A pipeline:
//   P) k_wprep:      pack W3/W4 into f16 hi/lo B-fragment order (one-time).
//   T) k_transpose1: feat1 (C,HW) -> featT (HW,C) per image.
//   Z) k_zero:       zero per-pixel consumer counts.
//   A) k_sims1T:     fp64 cosine sims + stable top-40 -> ids + consumer counts.
//   S) k_scan:       exclusive scan counts -> off, cursor (CSR).
//   F) k_fill:       slots[off[pix]+k] = out-row index (CSR fill).
//   B) k_mlp_fused:  dense MFMA MLP for ALL pixels + L2-norm, scatters rows
//      DIRECTLY into out1 via CSR (no ybuf round-trip).
// Tiers B/C/fallback: verified fp32 paths from earlier rounds.
// ===========================================================================

__global__ __launch_bounds__(256) void k_wprep(
    const float* __restrict__ W3, const float* __restrict__ W4,
    unsigned short* __restrict__ PB3h, unsigned short* __restrict__ PB3l,
    unsigned short* __restrict__ PB4h, unsigned short* __restrict__ PB4l)
{
    const int e = blockIdx.x * 256 + threadIdx.x;    // 0..65535
    if (e < 16384) {  // W3: 16 nt x 2 ks x 64 lanes x 8
        const int j = e & 7, l = (e >> 3) & 63, ks = (e >> 9) & 1, nt = e >> 10;
        const int n = nt * 16 + (l & 15);
        const int k = ks * 32 + (l >> 4) * 8 + j;
        const float w = W3[n * 64 + k];
        const _Float16 hi = (_Float16)w;
        const _Float16 lo = (_Float16)(w - (float)hi);
        ((_Float16*)PB3h)[e] = hi;
        ((_Float16*)PB3l)[e] = lo;
    }
    {  // W4: 16 nt x 8 ks x 64 lanes x 8
        const int j = e & 7, l = (e >> 3) & 63, ks = (e >> 9) & 7, nt = e >> 12;
        const int n = nt * 16 + (l & 15);
        const int k = ks * 32 + (l >> 4) * 8 + j;
        const float w = W4[n * 256 + k];
        const _Float16 hi = (_Float16)w;
        const _Float16 lo = (_Float16)(w - (float)hi);
        ((_Float16*)PB4h)[e] = hi;
        ((_Float16*)PB4l)[e] = lo;
    }
}

__global__ __launch_bounds__(256) void k_transpose1(
    const float* __restrict__ feat1, float* __restrict__ featT)
{
    __shared__ float tile[64][65];
    const int b = blockIdx.y;
    const int p0 = blockIdx.x * 64;
    const int tid = threadIdx.x;
    const float* fb = feat1 + (size_t)b * 64 * 16384;
    float* ft = featT + (size_t)b * 16384 * 64;
    #pragma unroll
    for (int it = 0; it < 16; ++it) {
        const int e = it * 256 + tid;
        const int c = e >> 6, p = e & 63;
        tile[p][c] = fb[(size_t)c * 16384 + p0 + p];
    }
    __syncthreads();
    #pragma unroll
    for (int it = 0; it < 16; ++it) {
        const int e = it * 256 + tid;
        const int p = e >> 6, c = e & 63;
        ft[(size_t)(p0 + p) * 64 + c] = tile[p][c];
    }
}

__global__ __launch_bounds__(256) void k_zero(unsigned* __restrict__ p, int n)
{
    const int i = blockIdx.x * 256 + threadIdx.x;
    if (i < n) p[i] = 0u;
}

__global__ __launch_bounds__(128) void k_sims1T(
    const float* __restrict__ featT, const int* __restrict__ patch_id1,
    const int* __restrict__ local_id1, int* __restrict__ idx,
    unsigned* __restrict__ cnt)
{
    __shared__ float cen[64];
    __shared__ double sims[80];
    __shared__ double cnorm;

    const int row = blockIdx.x;          // 0..4095
    const int b = row >> 9;
    const int n = row & 511;
    const int tid = threadIdx.x;
    const float* ft = featT + (size_t)b * 16384 * 64;
    const int pid = patch_id1[n];
    const int* lids = local_id1 + n * 80;

    if (tid < 64) cen[tid] = ft[(size_t)pid * 64 + tid];
    __syncthreads();

    if (tid < 64) {
        double v = (double)cen[tid];
        double s = v * v;
        for (int o = 32; o > 0; o >>= 1) s += __shfl_down(s, o);
        if (tid == 0) { s = sqrt(s); cnorm = (s < 1e-12) ? 1e-12 : s; }
    }
    __syncthreads();

    if (tid < 80) {
        const float4* rp = (const float4*)(ft + (size_t)lids[tid] * 64);
        double d = 0.0, q = 0.0;
        #pragma unroll
        for (int k = 0; k < 16; ++k) {
            const float4 v4 = rp[k];
            double v;
            v = (double)v4.x; d += v * (double)cen[4*k+0]; q += v*v;
            v = (double)v4.y; d += v * (double)cen[4*k+1]; q += v*v;
            v = (double)v4.z; d += v * (double)cen[4*k+2]; q += v*v;
            v = (double)v4.w; d += v * (double)cen[4*k+3]; q += v*v;
        }
        double nl = sqrt(q); if (nl < 1e-12) nl = 1e-12;
        sims[tid] = d / (nl * cnorm);
    }
    __syncthreads();

    if (tid < 80) {
        const double s = sims[tid];
        int rank = 0;
        for (int j = 0; j < 80; ++j) {
            const double sj = sims[j];
            rank += (sj > s) || (sj == s && j < tid);
        }
        if (rank < 40) {
            idx[row * 41 + 1 + rank] = lids[tid];
            atomicAdd(&cnt[b * 16384 + lids[tid]], 1u);
        }
    }
    if (tid == 0) {
        idx[row * 41] = pid;
        atomicAdd(&cnt[b * 16384 + pid], 1u);
    }
}

// exclusive scan of per-pixel counts (one block per image)
__global__ __launch_bounds__(256) void k_scan(
    const unsigned* __restrict__ cnt, unsigned* __restrict__ off,
    unsigned* __restrict__ cursor)
{
    __shared__ unsigned ssum[256];
    const int img = blockIdx.x;
    const int t = threadIdx.x;
    const unsigned* c = cnt + img * 16384;
    unsigned s = 0;
    for (int i = 0; i < 64; ++i) s += c[t * 64 + i];
    ssum[t] = s;
    __syncthreads();
    if (t == 0) {
        unsigned run = 0;
        for (int i = 0; i < 256; ++i) { const unsigned v = ssum[i]; ssum[i] = run; run += v; }
    }
    __syncthreads();
    unsigned run = ssum[t];
    unsigned* o  = off + img * 16384;
    unsigned* cu = cursor + img * 16384;
    for (int i = 0; i < 64; ++i) {
        const int p = t * 64 + i;
        o[p] = run; cu[p] = run;
        run += c[p];
    }
}

__global__ __launch_bounds__(256) void k_fill(
    const int* __restrict__ idx, unsigned* __restrict__ cursor,
    int* __restrict__ slots)
{
    const int e = blockIdx.x * 256 + threadIdx.x;
    if (e >= 4096 * 41) return;
    const int row = e / 41;
    const int img = row >> 9;
    const int pix = idx[e];
    const unsigned pos = atomicAdd(&cursor[img * 16384 + pix], 1u);
    slots[img * 20992 + pos] = e;
}

// ---------------------------------------------------------------------------
// MFMA MLP + fused scatter. 32 pixels/block, 256 thr = 4 waves.
// wave w: mt = w&1 (16 rows), nh = w>>1 (8 of 16 n-tiles).
// f16 hi/lo split: x*w ~= lo*hi + hi*lo + hi*hi, fp32 accumulate in MFMA.
// C/D layout: col = lane&15, row = (lane>>4)*4 + reg.
// T1 stored as f16 hi/lo pairs (identical values to split-on-read).
// X staging LDS is overlapped with T1 (X dead once A-frags are in regs).
// ---------------------------------------------------------------------------
__global__ __launch_bounds__(256, 4) void k_mlp_fused(
    const float* __restrict__ featb,
    const unsigned short* __restrict__ PB3h, const unsigned short* __restrict__ PB3l,
    const unsigned short* __restrict__ PB4h, const unsigned short* __restrict__ PB4l,
    const float* __restrict__ b3, const float* __restrict__ b4,
    const unsigned* __restrict__ cnt, const unsigned* __restrict__ off,
    const int* __restrict__ slots, float* __restrict__ out1)
{
    __shared__ __align__(16) unsigned char smem[33792];
    _Float16 (*XH)[72]  = (_Float16(*)[72])smem;            // 4608 B
    _Float16 (*XL)[72]  = (_Float16(*)[72])(smem + 4608);   // 4608 B
    _Float16 (*TH)[264] = (_Float16(*)[264])smem;           // 16896 B (overlaps X)
    _Float16 (*TL)[264] = (_Float16(*)[264])(smem + 16896); // 16896 B
    __shared__ float rsums[2][2][16];

    const int tid = threadIdx.x;
    const int blk = blockIdx.x;
    const int img = blk >> 9;
    const int p0 = (blk & 511) * 32;
    const float* fb = featb + (size_t)img * 64 * 16384;

    // X fill (coalesced) + f16 hi/lo split
    {
        const int p = tid & 31;
        const int cg = tid >> 5;
        #pragma unroll
        for (int k = 0; k < 8; ++k) {
            const int c = cg * 8 + k;
            const float v = fb[(size_t)c * 16384 + p0 + p];
            const _Float16 hi = (_Float16)v;
            XH[p][c] = hi;
            XL[p][c] = (_Float16)(v - (float)hi);
        }
    }
    __syncthreads();

    const int lane = tid & 63;
    const int w = tid >> 6;
    const int mt = w & 1;
    const int nh = w >> 1;
    const int lrow = lane & 15;
    const int kblk = lane >> 4;

    // A-fragments for stage 1 (into regs BEFORE X is overwritten by T1)
    f16x8 ah[2], al[2];
    #pragma unroll
    for (int ks = 0; ks < 2; ++ks) {
        ah[ks] = *(const f16x8*)&XH[mt*16 + lrow][ks*32 + kblk*8];
        al[ks] = *(const f16x8*)&XL[mt*16 + lrow][ks*32 + kblk*8];
    }
    __syncthreads();   // all waves done reading X

    // ---- stage 1: T1 = relu(X @ W3^T + b3), written as f16 hi/lo ----
    {
        const f16x8* B3H = (const f16x8*)PB3h;
        const f16x8* B3L = (const f16x8*)PB3l;
        #pragma unroll
        for (int t = 0; t < 8; ++t) {
            const int nt = nh*8 + t;
            const f16x8 bh0 = B3H[(nt*2 + 0)*64 + lane];
            const f16x8 bl0 = B3L[(nt*2 + 0)*64 + lane];
            const f16x8 bh1 = B3H[(nt*2 + 1)*64 + lane];
            const f16x8 bl1 = B3L[(nt*2 + 1)*64 + lane];
            f32x4 acc = {0.f, 0.f, 0.f, 0.f};
            acc = __builtin_amdgcn_mfma_f32_16x16x32_f16(al[0], bh0, acc, 0, 0, 0);
            acc = __builtin_amdgcn_mfma_f32_16x16x32_f16(ah[0], bl0, acc, 0, 0, 0);
            acc = __builtin_amdgcn_mfma_f32_16x16x32_f16(ah[0], bh0, acc, 0, 0, 0);
            acc = __builtin_amdgcn_mfma_f32_16x16x32_f16(al[1], bh1, acc, 0, 0, 0);
            acc = __builtin_amdgcn_mfma_f32_16x16x32_f16(ah[1], bl1, acc, 0, 0, 0);
            acc = __builtin_amdgcn_mfma_f32_16x16x32_f16(ah[1], bh1, acc, 0, 0, 0);
            const float bias = b3[nt*16 + lrow];
            #pragma unroll
            for (int r = 0; r < 4; ++r) {
                const float tv = fmaxf(acc[r] + bias, 0.f);
                const _Float16 hi = (_Float16)tv;
                TH[mt*16 + kblk*4 + r][nt*16 + lrow] = hi;
                TL[mt*16 + kblk*4 + r][nt*16 + lrow] = (_Float16)(tv - (float)hi);
            }
        }
    }
    __syncthreads();

    // ---- stage 2: Y = T1 @ W4^T + b4 ----
    f32x4 acc2[8];
    #pragma unroll
    for (int t = 0; t < 8; ++t) acc2[t] = (f32x4){0.f, 0.f, 0.f, 0.f};
    {
        const f16x8* B4H = (const f16x8*)PB4h;
        const f16x8* B4L = (const f16x8*)PB4l;
        #pragma unroll 2
        for (int ks = 0; ks < 8; ++ks) {
            const f16x8 a2h = *(const f16x8*)&TH[mt*16 + lrow][ks*32 + kblk*8];
            const f16x8 a2l = *(const f16x8*)&TL[mt*16 + lrow][ks*32 + kblk*8];
            #pragma unroll
            for (int th = 0; th < 2; ++th) {   // batch B loads 4 tiles ahead
                f16x8 bh[4], bl[4];
                #pragma unroll
                for (int q = 0; q < 4; ++q) {
                    const int nt = nh*8 + th*4 + q;
                    bh[q] = B4H[(nt*8 + ks)*64 + lane];
                    bl[q] = B4L[(nt*8 + ks)*64 + lane];
                }
                #pragma unroll
                for (int q = 0; q < 4; ++q) {
                    const int t = th*4 + q;
                    acc2[t] = __builtin_amdgcn_mfma_f32_16x16x32_f16(a2l, bh[q], acc2[t], 0, 0, 0);
                    acc2[t] = __builtin_amdgcn_mfma_f32_16x16x32_f16(a2h, bl[q], acc2[t], 0, 0, 0);
                    acc2[t] = __builtin_amdgcn_mfma_f32_16x16x32_f16(a2h, bh[q], acc2[t], 0, 0, 0);
                }
            }
        }
    }

    // bias + row sum of squares
    float p[4] = {0.f, 0.f, 0.f, 0.f};
    #pragma unroll
    for (int t = 0; t < 8; ++t) {
        const float bias = b4[(nh*8 + t)*16 + lrow];
        #pragma unroll
        for (int r = 0; r < 4; ++r) {
            acc2[t][r] += bias;
            p[r] += acc2[t][r] * acc2[t][r];
        }
    }
    #pragma unroll
    for (int r = 0; r < 4; ++r)
        for (int o = 1; o < 16; o <<= 1) p[r] += __shfl_xor(p[r], o);
    if (lrow == 0) {
        #pragma unroll
        for (int r = 0; r < 4; ++r) rsums[mt][nh][kblk*4 + r] = p[r];
    }
    __syncthreads();
    float inv[4];
    #pragma unroll
    for (int r = 0; r < 4; ++r) {
        const float s = rsums[mt][0][kblk*4 + r] + rsums[mt][1][kblk*4 + r];
        inv[r] = 1.f / (sqrtf(s) + 1e-7f);
    }

    // fused scatter: write normalized row to every consumer slot in out1
    const unsigned* cntp = cnt + img * 16384;
    const unsigned* offp = off + img * 16384;
    const int* slotp = slots + img * 20992;
    #pragma unroll
    for (int r = 0; r < 4; ++r) {
        const int row = mt*16 + kblk*4 + r;
        const int pix = p0 + row;
        const unsigned deg = cntp[pix];
        const unsigned st = offp[pix];
        float y[8];
        #pragma unroll
        for (int t = 0; t < 8; ++t) y[t] = acc2[t][r] * inv[r];
        for (unsigned s = 0; s < deg; ++s) {
            const int e = slotp[st + s];
            float* dst = out1 + (size_t)e * 256 + nh*128 + lrow;
            #pragma unroll
            for (int t = 0; t < 8; ++t) dst[t*16] = y[t];
        }
    }
}

// ===========================================================================
// Verified fallback paths (tiers B/C + original fused kernel)
// ===========================================================================
__global__ __launch_bounds__(128) void k_sims1(
    const float* __restrict__ feat1, const int* __restrict__ patch_id1,
    const int* __restrict__ local_id1, int* __restrict__ idx)
{
    __shared__ float cen[64];
    __shared__ double sims[80];
    __shared__ double cnorm;

    const int row = blockIdx.x;
    const int b = row >> 9;
    const int n = row & 511;
    const int tid = threadIdx.x;
    const float* fb = feat1 + (size_t)b * 64 * 16384;
    const int pid = patch_id1[n];
    const int* lids = local_id1 + n * 80;

    if (tid < 64) cen[tid] = fb[(size_t)tid * 16384 + pid];
    __syncthreads();

    if (tid < 64) {
        double v = (double)cen[tid];
        double s = v * v;
        for (int o = 32; o > 0; o >>= 1) s += __shfl_down(s, o);
        if (tid == 0) { s = sqrt(s); cnorm = (s < 1e-12) ? 1e-12 : s; }
    }
    __syncthreads();

    if (tid < 80) {
        const int lpix = lids[tid];
        double d = 0.0, q = 0.0;
        for (int c = 0; c < 64; ++c) {
            double v = (double)fb[(size_t)c * 16384 + lpix];
            d += v * (double)cen[c];
            q += v * v;
        }
        double nl = sqrt(q); if (nl < 1e-12) nl = 1e-12;
        sims[tid] = d / (nl * cnorm);
    }
    __syncthreads();

    if (tid < 80) {
        const double s = sims[tid];
        int rank = 0;
        for (int j = 0; j < 80; ++j) {
            const double sj = sims[j];
            rank += (sj > s) || (sj == s && j < tid);
        }
        if (rank < 40) idx[row * 41 + 1 + rank] = lids[tid];
    }
    if (tid == 0) idx[row * 41] = pid;
}

__global__ __launch_bounds__(256) void k_mlp_pix2(
    const float* __restrict__ featb,
    const float* __restrict__ W3T, const float* __restrict__ b3,
    const float* __restrict__ W4T, const float* __restrict__ b4,
    float* __restrict__ ybuf, int ybufStride)
{
    __shared__ __align__(16) float xs[32 * 68];
    __shared__ __align__(16) float t1s[32 * 256];

    const int tid = threadIdx.x;
    const int blk = blockIdx.x;
    const int img = blk >> 9;
    const int p0 = (blk & 511) * 32;
    const float* fb = featb + (size_t)img * 64 * 16384;
    float* yb = ybuf + (size_t)img * (size_t)ybufStride;

    {
        const int p = tid & 31;
        const int cg = tid >> 5;
        #pragma unroll
        for (int k = 0; k < 8; ++k) {
            const int c = cg * 8 + k;
            xs[p * 68 + c] = fb[(size_t)c * 16384 + p0 + p];
        }
    }
    __syncthreads();

    const int jg = tid & 63;
    const int g = tid >> 6;
    const int j0 = jg * 4;
    const int mb = g * 8;

    {
        float acc[8][4];
        #pragma unroll
        for (int r = 0; r < 8; ++r) {
            acc[r][0] = 0.f; acc[r][1] = 0.f; acc[r][2] = 0.f; acc[r][3] = 0.f;
        }
        const float4* Wf = (const float4*)W3T;
        const float4* xsf = (const float4*)xs;
        #pragma unroll 4
        for (int cq = 0; cq < 16; ++cq) {
            const float4 wA = Wf[(cq * 4 + 0) * 64 + jg];
            const float4 wB = Wf[(cq * 4 + 1) * 64 + jg];
            const float4 wC = Wf[(cq * 4 + 2) * 64 + jg];
            const float4 wD = Wf[(cq * 4 + 3) * 64 + jg];
            #pragma unroll
            for (int r = 0; r < 8; ++r) {
                const float4 x4 = xsf[(mb + r) * 17 + cq];
                acc[r][0] += x4.x*wA.x + x4.y*wB.x + x4.z*wC.x + x4.w*wD.x;
                acc[r][1] += x4.x*wA.y + x4.y*wB.y + x4.z*wC.y + x4.w*wD.y;
                acc[r][2] += x4.x*wA.z + x4.y*wB.z + x4.z*wC.z + x4.w*wD.z;
                acc[r][3] += x4.x*wA.w + x4.y*wB.w + x4.z*wC.w + x4.w*wD.w;
            }
        }
        const float bb0 = b3[j0], bb1 = b3[j0+1], bb2 = b3[j0+2], bb3 = b3[j0+3];
        #pragma unroll
        for (int r = 0; r < 8; ++r) {
            float4 o4;
            o4.x = fmaxf(acc[r][0] + bb0, 0.f);
            o4.y = fmaxf(acc[r][1] + bb1, 0.f);
            o4.z = fmaxf(acc[r][2] + bb2, 0.f);
            o4.w = fmaxf(acc[r][3] + bb3, 0.f);
            *(float4*)&t1s[(mb + r) * 256 + j0] = o4;
        }
    }
    __syncthreads();

    {
        float acc[8][4];
        #pragma unroll
        for (int r = 0; r < 8; ++r) {
            acc[r][0] = 0.f; acc[r][1] = 0.f; acc[r][2] = 0.f; acc[r][3] = 0.f;
        }
        const float4* Wf = (const float4*)W4T;
        const float4* t1f = (const float4*)t1s;
        #pragma unroll 2
        for (int kq = 0; kq < 64; ++kq) {
            const float4 wA = Wf[(kq * 4 + 0) * 64 + jg];
            const float4 wB = Wf[(kq * 4 + 1) * 64 + jg];
            const float4 wC = Wf[(kq * 4 + 2) * 64 + jg];
            const float4 wD = Wf[(kq * 4 + 3) * 64 + jg];
            #pragma unroll
            for (int r = 0; r < 8; ++r) {
                const float4 t4 = t1f[(mb + r) * 64 + kq];
                acc[r][0] += t4.x*wA.x + t4.y*wB.x + t4.z*wC.x + t4.w*wD.x;
                acc[r][1] += t4.x*wA.y + t4.y*wB.y + t4.z*wC.y + t4.w*wD.y;
                acc[r][2] += t4.x*wA.z + t4.y*wB.z + t4.z*wC.z + t4.w*wD.z;
                acc[r][3] += t4.x*wA.w + t4.y*wB.w + t4.z*wC.w + t4.w*wD.w;
            }
        }
        const float bb0 = b4[j0], bb1 = b4[j0+1], bb2 = b4[j0+2], bb3 = b4[j0+3];
        #pragma unroll
        for (int r = 0; r < 8; ++r) {
            const float y0 = acc[r][0] + bb0;
            const float y1 = acc[r][1] + bb1;
            const float y2 = acc[r][2] + bb2;
            const float y3 = acc[r][3] + bb3;
            float p = y0*y0 + y1*y1 + y2*y2 + y3*y3;
            for (int o = 1; o < 64; o <<= 1) p += __shfl_xor(p, o);
            const float inv = 1.f / (sqrtf(p) + 1e-7f);
            float4 o4 = make_float4(y0*inv, y1*inv, y2*inv, y3*inv);
            *(float4*)&yb[(size_t)(p0 + mb + r) * 256 + j0] = o4;
        }
    }
}

__global__ __launch_bounds__(256) void k_wtrans(
    const float* __restrict__ W3, const float* __restrict__ W4,
    float* __restrict__ W3T, float* __restrict__ W4T)
{
    const int t = threadIdx.x;
    const int j = blockIdx.x;
    W4T[(size_t)t * 256 + j] = W4[(size_t)j * 256 + t];
    if (j < 64) W3T[(size_t)j * 256 + t] = W3[(size_t)t * 64 + j];
}

__global__ __launch_bounds__(256) void k_gather1(
    const float* __restrict__ ybuf, int ybufStride,
    const int* __restrict__ idxb, float* __restrict__ out1b)
{
    __shared__ int pix[41];
    const int bn = blockIdx.x;
    const int img = bn >> 9;
    const int tid = threadIdx.x;
    if (tid < 41) pix[tid] = idxb[bn * 41 + tid];
    __syncthreads();
    const float4* yb4 = (const float4*)(ybuf + (size_t)img * (size_t)ybufStride);
    float4* o4 = (float4*)(out1b + (size_t)bn * 41 * 256);
    for (int e = tid; e < 41 * 64; e += 256) {
        const int mi = e >> 6, j4 = e & 63;
        o4[mi * 64 + j4] = yb4[pix[mi] * 64 + j4];
    }
}

__global__ __launch_bounds__(256) void k_branch1(
    const float* __restrict__ feat1, const int* __restrict__ patch_id1,
    const int* __restrict__ local_id1, const float* __restrict__ W3,
    const float* __restrict__ b3, const float* __restrict__ W4,
    const float* __restrict__ b4, float* __restrict__ out1)
{
    __shared__ __align__(16) float xs[44 * 64];
    __shared__ __align__(16) float t1s[44 * 256];
    __shared__ double sims[80];
    __shared__ int winners[40];
    __shared__ float cen[64];
    __shared__ double cnorm;

    const int row = blockIdx.x;
    const int b = row >> 9;
    const int n = row & 511;
    const int tid = threadIdx.x;
    const float* fb = feat1 + (size_t)b * 64 * 16384;
    const int pid = patch_id1[n];
    const int* lids = local_id1 + n * 80;

    if (tid < 64) cen[tid] = fb[(size_t)tid * 16384 + pid];
    __syncthreads();

    if (tid < 64) {
        double v = (double)cen[tid];
        double s = v * v;
        for (int o = 32; o > 0; o >>= 1) s += __shfl_down(s, o);
        if (tid == 0) { s = sqrt(s); cnorm = (s < 1e-12) ? 1e-12 : s; }
    }
    __syncthreads();

    if (tid < 80) {
        const int lpix = lids[tid];
        double d = 0.0, q = 0.0;
        for (int c = 0; c < 64; ++c) {
            double v = (double)fb[(size_t)c * 16384 + lpix];
            d += v * (double)cen[c];
            q += v * v;
        }
        double nl = sqrt(q); if (nl < 1e-12) nl = 1e-12;
        sims[tid] = d / (nl * cnorm);
    }
    __syncthreads();

    if (tid < 80) {
        const double s = sims[tid];
        int rank = 0;
        for (int j = 0; j < 80; ++j) {
            const double sj = sims[j];
            rank += (sj > s) || (sj == s && j < tid);
        }
        if (rank < 40) winners[rank] = tid;
    }
    __syncthreads();

    for (int m = tid; m < 44 * 64; m += 256) {
        const int mi = m >> 6, c = m & 63;
        float v;
        if (mi >= 1 && mi <= 40) v = fb[(size_t)c * 16384 + lids[winners[mi - 1]]];
        else v = cen[c];
        xs[m] = v;
    }
    __syncthreads();

    const int jg = tid & 63;
    const int g = tid >> 6;
    const int j0 = jg * 4;
    const int mb = g * 11;

    {
        float acc[11][4];
        #pragma unroll
        for (int r = 0; r < 11; ++r) {
            acc[r][0] = 0.f; acc[r][1] = 0.f; acc[r][2] = 0.f; acc[r][3] = 0.f;
        }
        const float4* W3f = (const float4*)W3;
        const float4* xsf = (const float4*)xs;
        #pragma unroll 4
        for (int c4 = 0; c4 < 16; ++c4) {
            const float4 w0 = W3f[(j0 + 0) * 16 + c4];
            const float4 w1 = W3f[(j0 + 1) * 16 + c4];
            const float4 w2 = W3f[(j0 + 2) * 16 + c4];
            const float4 w3 = W3f[(j0 + 3) * 16 + c4];
            #pragma unroll
            for (int r = 0; r < 11; ++r) {
                const float4 x4 = xsf[(mb + r) * 16 + c4];
                acc[r][0] += x4.x*w0.x + x4.y*w0.y + x4.z*w0.z + x4.w*w0.w;
                acc[r][1] += x4.x*w1.x + x4.y*w1.y + x4.z*w1.z + x4.w*w1.w;
                acc[r][2] += x4.x*w2.x + x4.y*w2.y + x4.z*w2.z + x4.w*w2.w;
                acc[r][3] += x4.x*w3.x + x4.y*w3.y + x4.z*w3.z + x4.w*w3.w;
            }
        }
        const float bb0 = b3[j0], bb1 = b3[j0+1], bb2 = b3[j0+2], bb3 = b3[j0+3];
        #pragma unroll
        for (int r = 0; r < 11; ++r) {
            float4 o4;
            o4.x = fmaxf(acc[r][0] + bb0, 0.f);
            o4.y = fmaxf(acc[r][1] + bb1, 0.f);
            o4.z = fmaxf(acc[r][2] + bb2, 0.f);
            o4.w = fmaxf(acc[r][3] + bb3, 0.f);
            *(float4*)&t1s[(mb + r) * 256 + j0] = o4;
        }
    }
    __syncthreads();

    {
        float acc[11][4];
        #pragma unroll
        for (int r = 0; r < 11; ++r) {
            acc[r][0] = 0.f; acc[r][1] = 0.f; acc[r][2] = 0.f; acc[r][3] = 0.f;
        }
        const float4* W4f = (const float4*)W4;
        const float4* t1f = (const float4*)t1s;
        #pragma unroll 2
        for (int j4 = 0; j4 < 64; ++j4) {
            const float4 w0 = W4f[(j0 + 0) * 64 + j4];
            const float4 w1 = W4f[(j0 + 1) * 64 + j4];
            const float4 w2 = W4f[(j0 + 2) * 64 + j4];
            const float4 w3 = W4f[(j0 + 3) * 64 + j4];
            #pragma unroll
            for (int r = 0; r < 11; ++r) {
                const float4 t4 = t1f[(mb + r) * 64 + j4];
                acc[r][0] += t4.x*w0.x + t4.y*w0.y + t4.z*w0.z + t4.w*w0.w;
                acc[r][1] += t4.x*w1.x + t4.y*w1.y + t4.z*w1.z + t4.w*w1.w;
                acc[r][2] += t4.x*w2.x + t4.y*w2.y + t4.z*w2.z + t4.w*w2.w;
                acc[r][3] += t4.x*w3.x + t4.y*w3.y + t4.z*w3.z + t4.w*w3.w;
            }
        }
        const float bb0 = b4[j0], bb1 = b4[j0+1], bb2 = b4[j0+2], bb3 = b4[j0+3];
        #pragma unroll
        for (int r = 0; r < 11; ++r) {
            const float y0 = acc[r][0] + bb0;
            const float y1 = acc[r][1] + bb1;
            const float y2 = acc[r][2] + bb2;
            const float y3 = acc[r][3] + bb3;
            float p = y0*y0 + y1*y1 + y2*y2 + y3*y3;
            for (int o = 1; o < 64; o <<= 1) p += __shfl_xor(p, o);
            const float inv = 1.f / (sqrtf(p) + 1e-7f);
            const int mi = mb + r;
            if (mi < 41) {
                float4 o4 = make_float4(y0*inv, y1*inv, y2*inv, y3*inv);
                *(float4*)&out1[((size_t)row * 41 + mi) * 256 + j0] = o4;
            }
        }
    }
}

// ---------------------------------------------------------------------------
// Branch 0 kernels
// ---------------------------------------------------------------------------
__global__ __launch_bounds__(64) void k_sample0(
    const float* __restrict__ feat0, const int* __restrict__ patch_id0,
    const int* __restrict__ local_id0, float* __restrict__ x0m)
{
    __shared__ float cen[512];
    __shared__ float loc[8][512];
    __shared__ double sims[8];
    __shared__ int winners[4];
    __shared__ double cnorm;

    const int row = blockIdx.x;
    const int b = row >> 6;
    const int n = row & 63;
    const int t = threadIdx.x;
    const float* fb = feat0 + (size_t)b * 512 * 64;
    const int pid = patch_id0[n];

    for (int c = t; c < 512; c += 64) cen[c] = fb[(size_t)c * 64 + pid];
    for (int l = 0; l < 8; ++l) {
        const int lp = local_id0[n * 8 + l];
        for (int c = t; c < 512; c += 64) loc[l][c] = fb[(size_t)c * 64 + lp];
    }
    __syncthreads();

    double cs = 0.0;
    for (int c = t; c < 512; c += 64) { double v = (double)cen[c]; cs += v * v; }
    for (int o = 32; o > 0; o >>= 1) cs += __shfl_down(cs, o);
    if (t == 0) { cs = sqrt(cs); cnorm = (cs < 1e-12) ? 1e-12 : cs; }
    __syncthreads();

    for (int l = 0; l < 8; ++l) {
        double d = 0.0, q = 0.0;
        for (int c = t; c < 512; c += 64) {
            double v = (double)loc[l][c];
            d += v * (double)cen[c];
            q += v * v;
        }
        for (int o = 32; o > 0; o >>= 1) { d += __shfl_down(d, o); q += __shfl_down(q, o); }
        if (t == 0) {
            double nl = sqrt(q); if (nl < 1e-12) nl = 1e-12;
            sims[l] = d / (nl * cnorm);
        }
    }
    __syncthreads();

    if (t < 8) {
        const double s = sims[t];
        int rank = 0;
        for (int j = 0; j < 8; ++j) {
            const double sj = sims[j];
            rank += (sj > s) || (sj == s && j < t);
        }
        if (rank < 4) winners[rank] = t;
    }
    __syncthreads();

    for (int c = t; c < 512; c += 64) {
        float a = cen[c];
        for (int r = 0; r < 4; ++r) a += loc[winners[r]][c];
        x0m[(size_t)row * 512 + c] = a * 0.2f;
    }
}

__global__ __launch_bounds__(128) void k_gemm1(
    const float* __restrict__ x, const float* __restrict__ W1,
    const float* __restrict__ b1, float* __restrict__ h)
{
    __shared__ __align__(16) float xsr[8 * 512];
    const int i0 = blockIdx.y * 8;
    const int tid = threadIdx.x;
    const int j0 = blockIdx.x * 512 + tid * 4;

    const float4* xg = (const float4*)(x + (size_t)i0 * 512);
    float4* xl = (float4*)xsr;
    #pragma unroll
    for (int e = 0; e < 8; ++e) xl[e * 128 + tid] = xg[e * 128 + tid];
    __syncthreads();

    float acc[8][4];
    #pragma unroll
    for (int r = 0; r < 8; ++r) {
        acc[r][0] = 0.f; acc[r][1] = 0.f; acc[r][2] = 0.f; acc[r][3] = 0.f;
    }
    const float4* W1f = (const float4*)W1;
    const float4* xf  = (const float4*)xsr;
    #pragma unroll 4
    for (int c4 = 0; c4 < 128; ++c4) {
        const float4 w0 = W1f[(size_t)(j0 + 0) * 128 + c4];
        const float4 w1 = W1f[(size_t)(j0 + 1) * 128 + c4];
        const float4 w2 = W1f[(size_t)(j0 + 2) * 128 + c4];
        const float4 w3 = W1f[(size_t)(j0 + 3) * 128 + c4];
        #pragma unroll
        for (int r = 0; r < 8; ++r) {
            const float4 x4 = xf[r * 128 + c4];
            acc[r][0] += x4.x*w0.x + x4.y*w0.y + x4.z*w0.z + x4.w*w0.w;
            acc[r][1] += x4.x*w1.x + x4.y*w1.y + x4.z*w1.z + x4.w*w1.w;
            acc[r][2] += x4.x*w2.x + x4.y*w2.y + x4.z*w2.z + x4.w*w2.w;
            acc[r][3] += x4.x*w3.x + x4.y*w3.y + x4.z*w3.z + x4.w*w3.w;
        }
    }
    const float bb0 = b1[j0], bb1 = b1[j0+1], bb2 = b1[j0+2], bb3 = b1[j0+3];
    #pragma unroll
    for (int r = 0; r < 8; ++r) {
        float4 o4 = make_float4(acc[r][0] + bb0, acc[r][1] + bb1,
                                acc[r][2] + bb2, acc[r][3] + bb3);
        *(float4*)&h[(size_t)(i0 + r) * 1024 + j0] = o4;
    }
}

__global__ __launch_bounds__(64) void k_bnstats(
    const float* __restrict__ h, float* __restrict__ mu, float* __restrict__ rstd)
{
    const int j = blockIdx.x;
    const int t = threadIdx.x;
    float s = 0.f, ss = 0.f;
    for (int i = t; i < 512; i += 64) {
        const float v = h[(size_t)i * 1024 + j];
        s += v; ss += v * v;
    }
    for (int o = 32; o > 0; o >>= 1) { s += __shfl_down(s, o); ss += __shfl_down(ss, o); }
    if (t == 0) {
        const float m = s * (1.f / 512.f);
        const float var = ss * (1.f / 512.f) - m * m;
        mu[j] = m;
        rstd[j] = rsqrtf(var + 1e-5f);
    }
}

__global__ __launch_bounds__(256) void k_bnapply(
    float* __restrict__ h, const float* __restrict__ mu, const float* __restrict__ rstd,
    const float* __restrict__ gamma, const float* __restrict__ beta)
{
    const int e = blockIdx.x * 256 + threadIdx.x;
    const int jb = (e & 255) * 4;
    float4 v = ((float4*)h)[e];
    v.x = fmaxf((v.x - mu[jb+0]) * rstd[jb+0] * gamma[jb+0] + beta[jb+0], 0.f);
    v.y = fmaxf((v.y - mu[jb+1]) * rstd[jb+1] * gamma[jb+1] + beta[jb+1], 0.f);
    v.z = fmaxf((v.z - mu[jb+2]) * rstd[jb+2] * gamma[jb+2] + beta[jb+2], 0.f);
    v.w = fmaxf((v.w - mu[jb+3]) * rstd[jb+3] * gamma[jb+3] + beta[jb+3], 0.f);
    ((float4*)h)[e] = v;
}

__global__ __launch_bounds__(256) void k_gemm2(
    const float* __restrict__ h, const float* __restrict__ W2,
    const float* __restrict__ b2, float* __restrict__ out0)
{
    __shared__ __align__(16) float hs[8 * 1024];
    const int i0 = blockIdx.x * 8;
    const int j = threadIdx.x;

    const float4* hg = (const float4*)(h + (size_t)i0 * 1024);
    float4* hl = (float4*)hs;
    #pragma unroll
    for (int e = 0; e < 8; ++e) hl[e * 256 + j] = hg[e * 256 + j];
    __syncthreads();

    float acc[8];
    #pragma unroll
    for (int r = 0; r < 8; ++r) acc[r] = 0.f;
    const float4* wr = (const float4*)(W2 + (size_t)j * 1024);
    const float4* hf = (const float4*)hs;
    #pragma unroll 4
    for (int k4 = 0; k4 < 256; ++k4) {
        const float4 w = wr[k4];
        #pragma unroll
        for (int r = 0; r < 8; ++r) {
            const float4 a = hf[r * 256 + k4];
            acc[r] += a.x*w.x + a.y*w.y + a.z*w.z + a.w*w.w;
        }
    }
    const float bb = b2[j];
    #pragma unroll
    for (int r = 0; r < 8; ++r)
        out0[(size_t)(i0 + r) * 256 + j] = acc[r] + bb;
}

// ---------------------------------------------------------------------------
extern "C" void kernel_launch(void* const* d_in, const int* in_sizes, int n_in,
                              void* d_out, int out_size, void* d_ws, size_t ws_size,
                              hipStream_t stream) {
    const float* feat0 = (const float*)d_in[0];
    const float* feat1 = (const float*)d_in[1];
    const float* W1    = (const float*)d_in[2];
    const float* b1    = (const float*)d_in[3];
    const float* gamma = (const float*)d_in[4];
    const float* beta  = (const float*)d_in[5];
    const float* W2    = (const float*)d_in[6];
    const float* b2    = (const float*)d_in[7];
    const float* W3    = (const float*)d_in[8];
    const float* b3    = (const float*)d_in[9];
    const float* W4    = (const float*)d_in[10];
    const float* b4    = (const float*)d_in[11];
    const int* patch_id0 = (const int*)d_in[12];
    const int* patch_id1 = (const int*)d_in[13];
    const int* local_id0 = (const int*)d_in[14];
    const int* local_id1 = (const int*)d_in[15];

    float* out0 = (float*)d_out;                 // (512, 256)
    float* out1 = out0 + 512 * 256;              // (4096, 41, 256)

    // workspace layout (float units)
    float* ws    = (float*)d_ws;
    float* x0m   = ws;                    // 262144
    float* h     = ws + 262144;           // 524288
    float* mu    = ws + 786432;           // 1024
    float* rstd  = ws + 787456;           // 1024
    int*   idx   = (int*)(ws + 788480);   // 167936 ints
    float* W3T   = ws + 956416;           // 16384   (fp32 path)
    float* W4T   = ws + 972800;           // 65536   (fp32 path)
    unsigned short* PB3h = (unsigned short*)(ws + 956416);   // MFMA path
    unsigned short* PB3l = PB3h + 16384;
    unsigned short* PB4h = PB3l + 16384;
    unsigned short* PB4l = PB4h + 65536;
    // tier A extras
    unsigned* cnt    = (unsigned*)(ws + 1038336);   // 131072 u32
    unsigned* off    = (unsigned*)(ws + 1169408);   // 131072 u32
    unsigned* cursor = (unsigned*)(ws + 1300480);   // 131072 u32
    int*      slots  = (int*)(ws + 1431552);        // 167936 ints
    float*    featTA = ws + 1599488;                // 8388608
    // tier B/C
    float* ybuf  = ws + 1038336;          // 16 MB per-image buffer
    const int YB_STRIDE = 16384 * 256;

    const size_t NEED_A = (size_t)(1599488 + 8388608) * 4;              // ~40 MB
    const size_t NEED_B = (size_t)(1038336 + 4194304 + 8388608) * 4;    // ~54.5 MB
    const size_t NEED_C = (size_t)(1038336 + 4194304) * 4;              // ~20.9 MB

    if (ws_size >= NEED_A) {
        // MFMA + fused-scatter path
        k_wprep<<<256, 256, 0, stream>>>(W3, W4, PB3h, PB3l, PB4h, PB4l);
        k_transpose1<<<dim3(256, 8), 256, 0, stream>>>(feat1, featTA);
        k_zero<<<512, 256, 0, stream>>>(cnt, 131072);
        k_sims1T<<<4096, 128, 0, stream>>>(featTA, patch_id1, local_id1, idx, cnt);
        k_scan<<<8, 256, 0, stream>>>(cnt, off, cursor);
        k_fill<<<656, 256, 0, stream>>>(idx, cursor, slots);
        k_mlp_fused<<<4096, 256, 0, stream>>>(feat1, PB3h, PB3l, PB4h, PB4l,
                                              b3, b4, cnt, off, slots, out1);
    } else if (ws_size >= NEED_C) {
        k_wtrans<<<256, 256, 0, stream>>>(W3, W4, W3T, W4T);
        k_sims1<<<4096, 128, 0, stream>>>(feat1, patch_id1, local_id1, idx);
        for (int b = 0; b < 8; ++b) {
            k_mlp_pix2<<<512, 256, 0, stream>>>(
                feat1 + (size_t)b * 64 * 16384, W3T, b3, W4T, b4, ybuf, 0);
            k_gather1<<<512, 256, 0, stream>>>(
                ybuf, 0, idx + (size_t)b * 512 * 41,
                out1 + (size_t)b * 512 * 41 * 256);
        }
    } else {
        k_branch1<<<4096, 256, 0, stream>>>(feat1, patch_id1, local_id1,
                                            W3, b3, W4, b4, out1);
    }

    // branch 0 chain
    k_sample0<<<512, 64, 0, stream>>>(feat0, patch_id0, local_id0, x0m);
    k_gemm1<<<dim3(2, 64), 128, 0, stream>>>(x0m, W1, b1, h);
    k_bnstats<<<1024, 64, 0, stream>>>(h, mu, rstd);
    k_bnapply<<<512, 256, 0, stream>>>(h, mu, rstd, gamma, beta);
    k_gemm2<<<64, 256, 0, stream>>>(h, W2, b2, out0);
}